// Round 13
// baseline (796.213 us; speedup 1.0000x reference)
//
#include <hip/hip_runtime.h>

// GIN forward, MI355X. Round 13:
//  - GEMMs reverted to R8 exact (4x4 reg-block, A^T + W in LDS; out1=67us proven;
//    R9-R12 variants all regressed: SMEM-W shares lgkmcnt, 8x4 loses occupancy,
//    global-W stalls on 64 in-loop vmcnt).
//  - NEW k_agg_gemm: fuses aggregation + gemm1. Per 64-node block: 4 waves each
//    gather 16 nodes (R7 float4-lane structure) writing aggregated rows DIRECTLY
//    into sAT (transposed, stride-65 -> 2-way free), then R8 GEMM phase + fused
//    stats. Kills o write+read (51MB/layer x3), 3 launches, and overlaps gather
//    latency with GEMM compute across co-resident blocks.
//  - partial stats + k_redstats (R6); bucketed CSR (R3).

#define HID 64
#define LAYERS 3
#define BN_EPS 1e-5f

#define BK_SHIFT 8          // 256 nodes per bucket
#define BK_MAX 512          // max buckets supported (N <= 131072)
#define PART_EPT 16         // edges per thread in k_bpart

__device__ __forceinline__ float relu_aff(float x, float s, float t) {
    return fmaxf(fmaf(x, s, t), 0.f);
}

__device__ __forceinline__ void bn_fin(const float* __restrict__ raw, const float* __restrict__ g,
                                       const float* __restrict__ b, float invN, int c,
                                       float& s, float& t) {
    float m = raw[c] * invN;
    float v = fmaf(-m, m, raw[64 + c] * invN);
    float r = rsqrtf(v + BN_EPS);
    s = r * g[c];
    t = fmaf(-m, s, b[c]);
}

// ---------------- bucketed CSR build ----------------

__global__ __launch_bounds__(256) void k_bhist(const int* __restrict__ dst, int* __restrict__ gh,
                                               int E, int nbk) {
    __shared__ int h[BK_MAX];
    for (int i = threadIdx.x; i < BK_MAX; i += 256) h[i] = 0;
    __syncthreads();
    int stride = gridDim.x * 256;
    for (int e = blockIdx.x * 256 + threadIdx.x; e < E; e += stride)
        atomicAdd(&h[dst[e] >> BK_SHIFT], 1);
    __syncthreads();
    for (int i = threadIdx.x; i < nbk; i += 256)
        if (h[i]) atomicAdd(&gh[i], h[i]);
}

__global__ __launch_bounds__(512) void k_bscan(const int* __restrict__ gh, int* __restrict__ boff,
                                               int* __restrict__ gcur, int nbk) {
    int lane = threadIdx.x & 63, wid = threadIdx.x >> 6;
    int v = (threadIdx.x < nbk) ? gh[threadIdx.x] : 0;
    int incl = v;
    for (int d = 1; d < 64; d <<= 1) { int y = __shfl_up(incl, d); if (lane >= d) incl += y; }
    __shared__ int ws[8];
    if (lane == 63) ws[wid] = incl;
    __syncthreads();
    if (threadIdx.x == 0) { int a = 0; for (int w = 0; w < 8; w++) { int t = ws[w]; ws[w] = a; a += t; } }
    __syncthreads();
    int excl = incl - v + ws[wid];
    if (threadIdx.x < nbk) { boff[threadIdx.x] = excl; gcur[threadIdx.x] = excl; }
    if (threadIdx.x == nbk - 1) boff[nbk] = excl + v;
}

__global__ __launch_bounds__(256) void k_bpart(const int* __restrict__ src, const int* __restrict__ dst,
                                               int* __restrict__ gcur, unsigned* __restrict__ pairs,
                                               int E) {
    __shared__ int h[BK_MAX], cur[BK_MAX], base[BK_MAX];
    int e0 = blockIdx.x * (256 * PART_EPT);
    int eend = min(e0 + 256 * PART_EPT, E);
    for (int i = threadIdx.x; i < BK_MAX; i += 256) h[i] = 0;
    __syncthreads();
    for (int e = e0 + threadIdx.x; e < eend; e += 256)
        atomicAdd(&h[dst[e] >> BK_SHIFT], 1);
    __syncthreads();
    for (int i = threadIdx.x; i < BK_MAX; i += 256) {
        cur[i] = 0;
        base[i] = h[i] ? atomicAdd(&gcur[i], h[i]) : 0;
    }
    __syncthreads();
    for (int e = e0 + threadIdx.x; e < eend; e += 256) {
        int d = dst[e];
        int b = d >> BK_SHIFT;
        int r = atomicAdd(&cur[b], 1);
        pairs[base[b] + r] = ((unsigned)(d & ((1 << BK_SHIFT) - 1)) << 24) | (unsigned)src[e];
    }
}

__global__ __launch_bounds__(256) void k_bucket_csr(const unsigned* __restrict__ pairs,
                                                    const int* __restrict__ boff,
                                                    int* __restrict__ row_off, int* __restrict__ col,
                                                    int N, int E, int nbk) {
    int b = blockIdx.x;
    int p0 = boff[b], p1 = boff[b + 1];
    int base_node = b << BK_SHIFT;
    int nn = min(256, N - base_node);
    __shared__ int h[256], cur[256];
    h[threadIdx.x] = 0;
    __syncthreads();
    for (int p = p0 + threadIdx.x; p < p1; p += 256)
        atomicAdd(&h[pairs[p] >> 24], 1);
    __syncthreads();
    int v = h[threadIdx.x];
    int lane = threadIdx.x & 63, wid = threadIdx.x >> 6;
    int incl = v;
    for (int d = 1; d < 64; d <<= 1) { int y = __shfl_up(incl, d); if (lane >= d) incl += y; }
    __shared__ int ws[4];
    if (lane == 63) ws[wid] = incl;
    __syncthreads();
    if (threadIdx.x == 0) { int a = 0; for (int w = 0; w < 4; w++) { int t = ws[w]; ws[w] = a; a += t; } }
    __syncthreads();
    int excl = incl - v + ws[wid];
    if (threadIdx.x < nn) row_off[base_node + threadIdx.x] = p0 + excl;
    if (b == nbk - 1 && threadIdx.x == 0) row_off[N] = E;
    cur[threadIdx.x] = excl;
    __syncthreads();
    for (int p = p0 + threadIdx.x; p < p1; p += 256) {
        unsigned pk = pairs[p];
        int local = pk >> 24;
        int r = atomicAdd(&cur[local], 1);
        col[p0 + r] = (int)(pk & 0xFFFFFFu);
    }
}

// ---------------- partial-stats reduce ----------------
__global__ __launch_bounds__(256) void k_redstats(const float* __restrict__ pst,
                                                  float* __restrict__ rawOut, int nblk) {
    int slot = blockIdx.x * 4 + (threadIdx.x >> 6);  // 0..127
    int lane = threadIdx.x & 63;
    float s = 0.f;
    for (int b = lane; b < nblk; b += 64) s += pst[(size_t)b * 128 + slot];
#pragma unroll
    for (int m = 1; m < 64; m <<= 1) s += __shfl_xor(s, m, 64);
    if (lane == 0) rawOut[slot] = s;
}

// ---------------- 4x4 register-blocked GEMM core (R8, proven) ----------------
#define GEMM44_COMPUTE(sAT, sW, acc, r0, c0)                                \
    _Pragma("unroll 8")                                                     \
    for (int k = 0; k < HID; k++) {                                         \
        float4 a = *(const float4*)&sAT[k * 65 + r0];                       \
        float4 w = *(const float4*)&sW[k * HID + c0];                       \
        acc[0]  = fmaf(a.x, w.x, acc[0]);  acc[1]  = fmaf(a.x, w.y, acc[1]);\
        acc[2]  = fmaf(a.x, w.z, acc[2]);  acc[3]  = fmaf(a.x, w.w, acc[3]);\
        acc[4]  = fmaf(a.y, w.x, acc[4]);  acc[5]  = fmaf(a.y, w.y, acc[5]);\
        acc[6]  = fmaf(a.y, w.z, acc[6]);  acc[7]  = fmaf(a.y, w.w, acc[7]);\
        acc[8]  = fmaf(a.z, w.x, acc[8]);  acc[9]  = fmaf(a.z, w.y, acc[9]);\
        acc[10] = fmaf(a.z, w.z, acc[10]); acc[11] = fmaf(a.z, w.w, acc[11]);\
        acc[12] = fmaf(a.w, w.x, acc[12]); acc[13] = fmaf(a.w, w.y, acc[13]);\
        acc[14] = fmaf(a.w, w.z, acc[14]); acc[15] = fmaf(a.w, w.w, acc[15]);\
    }

// shared epilogue: bias add, C write, per-column stats partials
#define GEMM44_EPILOGUE(STATS_ON)                                            \
    {                                                                        \
        float4 bs = *(const float4*)&bias[c0];                               \
        float sc[4] = {0.f, 0.f, 0.f, 0.f}, sq[4] = {0.f, 0.f, 0.f, 0.f};    \
        _Pragma("unroll")                                                    \
        for (int ri = 0; ri < 4; ri++) {                                     \
            int row = base + r0 + ri;                                        \
            if (row < n) {                                                   \
                float4 v;                                                    \
                v.x = acc[ri * 4 + 0] + bs.x;                                \
                v.y = acc[ri * 4 + 1] + bs.y;                                \
                v.z = acc[ri * 4 + 2] + bs.z;                                \
                v.w = acc[ri * 4 + 3] + bs.w;                                \
                *(float4*)&C[(size_t)row * HID + c0] = v;                    \
                if (STATS_ON) {                                              \
                    sc[0] += v.x; sq[0] = fmaf(v.x, v.x, sq[0]);             \
                    sc[1] += v.y; sq[1] = fmaf(v.y, v.y, sq[1]);             \
                    sc[2] += v.z; sq[2] = fmaf(v.z, v.z, sq[2]);             \
                    sc[3] += v.w; sq[3] = fmaf(v.w, v.w, sq[3]);             \
                }                                                            \
            }                                                                \
        }                                                                    \
        if (STATS_ON) {                                                      \
            int lane = threadIdx.x & 63, wv = threadIdx.x >> 6;              \
            _Pragma("unroll")                                                \
            for (int j = 0; j < 4; j++) {                                    \
                sc[j] += __shfl_xor(sc[j], 16, 64); sc[j] += __shfl_xor(sc[j], 32, 64); \
                sq[j] += __shfl_xor(sq[j], 16, 64); sq[j] += __shfl_xor(sq[j], 32, 64); \
            }                                                                \
            if (lane < 16) {                                                 \
                *(float4*)&ps[wv][c0] = make_float4(sc[0], sc[1], sc[2], sc[3]); \
                *(float4*)&pq[wv][c0] = make_float4(sq[0], sq[1], sq[2], sq[3]); \
            }                                                                \
            __syncthreads();                                                 \
            if (threadIdx.x < 64) {                                          \
                float s = ps[0][threadIdx.x] + ps[1][threadIdx.x] + ps[2][threadIdx.x] + ps[3][threadIdx.x]; \
                float q = pq[0][threadIdx.x] + pq[1][threadIdx.x] + pq[2][threadIdx.x] + pq[3][threadIdx.x]; \
                pst[(size_t)blockIdx.x * 128 + threadIdx.x] = s;             \
                pst[(size_t)blockIdx.x * 128 + 64 + threadIdx.x] = q;        \
            }                                                                \
        }                                                                    \
    }

// tiled GEMM: C[n x 64] = act(A[n x 64]) @ W[64 x 64] + bias
template <bool AFF, bool STATS>
__global__ __launch_bounds__(256) void k_gemm_t64(const float* __restrict__ A,
                                                  const float* __restrict__ raw, const float* __restrict__ g,
                                                  const float* __restrict__ b, float invN,
                                                  const float* __restrict__ W, const float* __restrict__ bias,
                                                  float* __restrict__ C, float* __restrict__ pst, int n) {
    __shared__ float stl[2 * HID];
    __shared__ float sAT[HID * 65];
    __shared__ float sW[HID * HID];
    __shared__ float ps[4][HID], pq[4][HID];
    if (AFF) {
        if (threadIdx.x < HID) {
            float s, t;
            bn_fin(raw, g, b, invN, threadIdx.x, s, t);
            stl[threadIdx.x] = s;
            stl[HID + threadIdx.x] = t;
        }
        __syncthreads();
    }
    int base = blockIdx.x * 64;
#pragma unroll
    for (int it = 0; it < 4; it++) {                      // stage W
        int idx = it * 256 + threadIdx.x;
        *(float4*)&sW[idx * 4] = *(const float4*)&W[idx * 4];
    }
#pragma unroll
    for (int it = 0; it < 4; it++) {                      // stage A^T (+act), zero-fill
        int idx = it * 256 + threadIdx.x;
        int r = idx >> 4;
        int kc = (idx & 15) * 4;
        float4 v = make_float4(0.f, 0.f, 0.f, 0.f);
        if (base + r < n) {
            v = *(const float4*)&A[(size_t)(base + r) * HID + kc];
            if (AFF) {
                v.x = relu_aff(v.x, stl[kc + 0], stl[HID + kc + 0]);
                v.y = relu_aff(v.y, stl[kc + 1], stl[HID + kc + 1]);
                v.z = relu_aff(v.z, stl[kc + 2], stl[HID + kc + 2]);
                v.w = relu_aff(v.w, stl[kc + 3], stl[HID + kc + 3]);
            }
        }
        sAT[(kc + 0) * 65 + r] = v.x;
        sAT[(kc + 1) * 65 + r] = v.y;
        sAT[(kc + 2) * 65 + r] = v.z;
        sAT[(kc + 3) * 65 + r] = v.w;
    }
    __syncthreads();

    int c0 = (threadIdx.x & 15) * 4;
    int r0 = (threadIdx.x >> 4) * 4;
    float acc[16];
#pragma unroll
    for (int j = 0; j < 16; j++) acc[j] = 0.f;
    GEMM44_COMPUTE(sAT, sW, acc, r0, c0)
    GEMM44_EPILOGUE(STATS)
}

// FUSED aggregation + gemm1: per 64-node tile, gather o = (1+eps)*act(h) + sum act(h[src])
// straight into sAT (transposed), then C = o @ W + bias with fused stats.
__global__ __launch_bounds__(256) void k_agg_gemm(const float* __restrict__ hb,
                                                  const float* __restrict__ rawH, const float* __restrict__ gH,
                                                  const float* __restrict__ bH, float invN,
                                                  const int* __restrict__ row_off, const int* __restrict__ col,
                                                  const float* __restrict__ epsp, int li,
                                                  const float* __restrict__ W, const float* __restrict__ bias,
                                                  float* __restrict__ C, float* __restrict__ pst, int n) {
    __shared__ float sAT[HID * 65];
    __shared__ float sW[HID * HID];
    __shared__ float ps[4][HID], pq[4][HID];

    int base = blockIdx.x * 64;
    int lane = threadIdx.x & 63, wv = threadIdx.x >> 6;
    int sub = lane >> 4;
    int fc = (lane & 15) * 4;

#pragma unroll
    for (int it = 0; it < 4; it++) {                      // stage W early (independent)
        int idx = it * 256 + threadIdx.x;
        *(float4*)&sW[idx * 4] = *(const float4*)&W[idx * 4];
    }

    float s0, t0, s1, t1, s2, t2, s3, t3;
    bn_fin(rawH, gH, bH, invN, fc + 0, s0, t0);
    bn_fin(rawH, gH, bH, invN, fc + 1, s1, t1);
    bn_fin(rawH, gH, bH, invN, fc + 2, s2, t2);
    bn_fin(rawH, gH, bH, invN, fc + 3, s3, t3);
    float ope = 1.f + epsp[li];

    // gather phase: wave wv aggregates nodes [base+16wv, base+16wv+16)
    for (int ii = 0; ii < 16; ii++) {
        int r = wv * 16 + ii;
        int node = base + r;                               // wave-uniform
        float ax = 0.f, ay = 0.f, az = 0.f, aw = 0.f;
        if (node < n) {
            int e = row_off[node], e1 = row_off[node + 1];
            while (e + 16 <= e1) {
                int i0 = col[e + sub], i1 = col[e + 4 + sub];
                int i2 = col[e + 8 + sub], i3 = col[e + 12 + sub];
                float4 v0 = *(const float4*)&hb[(size_t)i0 * HID + fc];
                float4 v1 = *(const float4*)&hb[(size_t)i1 * HID + fc];
                float4 v2 = *(const float4*)&hb[(size_t)i2 * HID + fc];
                float4 v3 = *(const float4*)&hb[(size_t)i3 * HID + fc];
                ax += relu_aff(v0.x, s0, t0) + relu_aff(v1.x, s0, t0) + relu_aff(v2.x, s0, t0) + relu_aff(v3.x, s0, t0);
                ay += relu_aff(v0.y, s1, t1) + relu_aff(v1.y, s1, t1) + relu_aff(v2.y, s1, t1) + relu_aff(v3.y, s1, t1);
                az += relu_aff(v0.z, s2, t2) + relu_aff(v1.z, s2, t2) + relu_aff(v2.z, s2, t2) + relu_aff(v3.z, s2, t2);
                aw += relu_aff(v0.w, s3, t3) + relu_aff(v1.w, s3, t3) + relu_aff(v2.w, s3, t3) + relu_aff(v3.w, s3, t3);
                e += 16;
            }
            while (e + 4 <= e1) {
                int i = col[e + sub];
                float4 v = *(const float4*)&hb[(size_t)i * HID + fc];
                ax += relu_aff(v.x, s0, t0);
                ay += relu_aff(v.y, s1, t1);
                az += relu_aff(v.z, s2, t2);
                aw += relu_aff(v.w, s3, t3);
                e += 4;
            }
            int rem = e1 - e;
            if (sub < rem) {
                int i = col[e + sub];
                float4 v = *(const float4*)&hb[(size_t)i * HID + fc];
                ax += relu_aff(v.x, s0, t0);
                ay += relu_aff(v.y, s1, t1);
                az += relu_aff(v.z, s2, t2);
                aw += relu_aff(v.w, s3, t3);
            }
        }
        ax += __shfl_xor(ax, 16, 64); ay += __shfl_xor(ay, 16, 64);
        az += __shfl_xor(az, 16, 64); aw += __shfl_xor(aw, 16, 64);
        ax += __shfl_xor(ax, 32, 64); ay += __shfl_xor(ay, 32, 64);
        az += __shfl_xor(az, 32, 64); aw += __shfl_xor(aw, 32, 64);
        if (sub == 0) {
            if (node < n) {
                float4 h4 = *(const float4*)&hb[(size_t)node * HID + fc];
                ax = fmaf(ope, relu_aff(h4.x, s0, t0), ax);
                ay = fmaf(ope, relu_aff(h4.y, s1, t1), ay);
                az = fmaf(ope, relu_aff(h4.z, s2, t2), az);
                aw = fmaf(ope, relu_aff(h4.w, s3, t3), aw);
            }
            sAT[(fc + 0) * 65 + r] = ax;   // stride-65 writes: 2-way bank (free)
            sAT[(fc + 1) * 65 + r] = ay;
            sAT[(fc + 2) * 65 + r] = az;
            sAT[(fc + 3) * 65 + r] = aw;
        }
    }
    __syncthreads();

    // GEMM phase (R8 4x4)
    int c0 = (threadIdx.x & 15) * 4;
    int r0 = (threadIdx.x >> 4) * 4;
    float acc[16];
#pragma unroll
    for (int j = 0; j < 16; j++) acc[j] = 0.f;
    GEMM44_COMPUTE(sAT, sW, acc, r0, c0)
    GEMM44_EPILOGUE(true)
}

// concat GEMM: C = [act(B0)|act(B1)|act(B2)|act(B3)] @ W[256 x 64] + bias, partial stats
__global__ __launch_bounds__(256) void k_gemm_out1_t(const float* __restrict__ B0, const float* __restrict__ B1,
                                                     const float* __restrict__ B2, const float* __restrict__ B3,
                                                     const float* __restrict__ R0, const float* __restrict__ R1,
                                                     const float* __restrict__ R2, const float* __restrict__ R3,
                                                     const float* __restrict__ G0, const float* __restrict__ G1,
                                                     const float* __restrict__ G2, const float* __restrict__ G3,
                                                     const float* __restrict__ E0, const float* __restrict__ E1,
                                                     const float* __restrict__ E2, const float* __restrict__ E3,
                                                     float invN,
                                                     const float* __restrict__ W, const float* __restrict__ bias,
                                                     float* __restrict__ C, float* __restrict__ pst, int n) {
    __shared__ float stl[4][2 * HID];
    __shared__ float sAT[HID * 65];
    __shared__ float sW[HID * HID];
    __shared__ float ps[4][HID], pq[4][HID];
    {
        int p = threadIdx.x >> 6, c = threadIdx.x & 63;
        const float* rp[4] = {R0, R1, R2, R3};
        const float* gp[4] = {G0, G1, G2, G3};
        const float* ep[4] = {E0, E1, E2, E3};
        float s, t;
        bn_fin(rp[p], gp[p], ep[p], invN, c, s, t);
        stl[p][c] = s;
        stl[p][HID + c] = t;
    }
    __syncthreads();

    int base = blockIdx.x * 64;
    int c0 = (threadIdx.x & 15) * 4;
    int r0 = (threadIdx.x >> 4) * 4;
    float acc[16];
#pragma unroll
    for (int j = 0; j < 16; j++) acc[j] = 0.f;
    const float* bufs[4] = {B0, B1, B2, B3};
#pragma unroll
    for (int pp = 0; pp < 4; pp++) {
        if (pp) __syncthreads();                          // WAR before restage
        const float* Bp = bufs[pp];
        const float* Wp = W + (size_t)pp * HID * HID;
#pragma unroll
        for (int it = 0; it < 4; it++) {
            int idx = it * 256 + threadIdx.x;
            *(float4*)&sW[idx * 4] = *(const float4*)&Wp[idx * 4];
        }
#pragma unroll
        for (int it = 0; it < 4; it++) {
            int idx = it * 256 + threadIdx.x;
            int r = idx >> 4;
            int kc = (idx & 15) * 4;
            float4 v = make_float4(0.f, 0.f, 0.f, 0.f);
            if (base + r < n) {
                v = *(const float4*)&Bp[(size_t)(base + r) * HID + kc];
                v.x = relu_aff(v.x, stl[pp][kc + 0], stl[pp][HID + kc + 0]);
                v.y = relu_aff(v.y, stl[pp][kc + 1], stl[pp][HID + kc + 1]);
                v.z = relu_aff(v.z, stl[pp][kc + 2], stl[pp][HID + kc + 2]);
                v.w = relu_aff(v.w, stl[pp][kc + 3], stl[pp][HID + kc + 3]);
            }
            sAT[(kc + 0) * 65 + r] = v.x;
            sAT[(kc + 1) * 65 + r] = v.y;
            sAT[(kc + 2) * 65 + r] = v.z;
            sAT[(kc + 3) * 65 + r] = v.w;
        }
        __syncthreads();
        GEMM44_COMPUTE(sAT, sW, acc, r0, c0)
    }
    GEMM44_EPILOGUE(true)
}

// final GEMM: C[n x 10] = act(A[n x 64]) @ W[64 x 10] + bias. K split across 4 waves.
__global__ __launch_bounds__(256) void k_gemm_out2_t(const float* __restrict__ A,
                                                     const float* __restrict__ raw, const float* __restrict__ g,
                                                     const float* __restrict__ b, float invN,
                                                     const float* __restrict__ W, const float* __restrict__ bias,
                                                     float* __restrict__ C, int n) {
    __shared__ float stl[2 * HID];
    if (threadIdx.x < HID) {
        float s, t;
        bn_fin(raw, g, b, invN, threadIdx.x, s, t);
        stl[threadIdx.x] = s;
        stl[HID + threadIdx.x] = t;
    }
    __syncthreads();
    int lane = threadIdx.x & 63;
    int wv = threadIdx.x >> 6;
    int k0 = __builtin_amdgcn_readfirstlane(wv * 16);
    int row = blockIdx.x * 64 + lane;
    bool valid = row < n;
    float acc[10];
#pragma unroll
    for (int j = 0; j < 10; j++) acc[j] = 0.f;
    if (valid) {
        const float4* a4 = (const float4*)(A + (size_t)row * HID + k0);
#pragma unroll
        for (int kk = 0; kk < 4; kk++) {
            float4 av = a4[kk];
            float a[4] = {av.x, av.y, av.z, av.w};
#pragma unroll
            for (int u = 0; u < 4; u++) {
                int k = k0 + kk * 4 + u;
                float xv = relu_aff(a[u], stl[k], stl[HID + k]);
#pragma unroll
                for (int j = 0; j < 10; j++) acc[j] = fmaf(xv, W[k * 10 + j], acc[j]);
            }
        }
    }
    __shared__ float part[4][64][10];
#pragma unroll
    for (int j = 0; j < 10; j++) part[wv][lane][j] = acc[j];
    __syncthreads();
    if (wv == 0 && valid) {
        float* cp = C + (size_t)row * 10;
#pragma unroll
        for (int j = 0; j < 10; j++)
            cp[j] = bias[j] + part[0][lane][j] + part[1][lane][j] + part[2][lane][j] + part[3][lane][j];
    }
}

// in-place z = relu_aff(x, s2, t2) + partial stats of z into pst
__global__ __launch_bounds__(256) void k_affine_stats(float* __restrict__ X,
                                                      const float* __restrict__ rawIn,
                                                      const float* __restrict__ g, const float* __restrict__ b,
                                                      float invN,
                                                      float* __restrict__ pst, long long n64) {
    long long stride = (long long)gridDim.x * 256;
    long long i0 = (long long)blockIdx.x * 256 + threadIdx.x;
    int col = threadIdx.x & 63;
    float sA, tA;
    bn_fin(rawIn, g, b, invN, col, sA, tA);
    float s = 0.f, q = 0.f;
    for (long long i = i0; i < n64; i += stride) {
        float v = relu_aff(X[i], sA, tA);
        X[i] = v;
        s += v; q = fmaf(v, v, q);
    }
    __shared__ float ls[256], lq[256];
    ls[threadIdx.x] = s; lq[threadIdx.x] = q;
    __syncthreads();
    if (threadIdx.x < 64) {
        s = ls[threadIdx.x] + ls[threadIdx.x + 64] + ls[threadIdx.x + 128] + ls[threadIdx.x + 192];
        q = lq[threadIdx.x] + lq[threadIdx.x + 64] + lq[threadIdx.x + 128] + lq[threadIdx.x + 192];
        pst[(size_t)blockIdx.x * 128 + col] = s;
        pst[(size_t)blockIdx.x * 128 + 64 + col] = q;
    }
}

extern "C" void kernel_launch(void* const* d_in, const int* in_sizes, int n_in,
                              void* d_out, int out_size, void* d_ws, size_t ws_size,
                              hipStream_t stream) {
    const float* x = (const float*)d_in[0];
    const int* ei = (const int*)d_in[1];
    const float* W_in = (const float*)d_in[2];
    const float* b_in = (const float*)d_in[3];
    const float* g_in = (const float*)d_in[4];
    const float* be_in = (const float*)d_in[5];
    const float* epsp = (const float*)d_in[6];
    const float* W1 = (const float*)d_in[7];
    const float* b1 = (const float*)d_in[8];
    const float* g1 = (const float*)d_in[9];
    const float* be1 = (const float*)d_in[10];
    const float* W2 = (const float*)d_in[11];
    const float* b2 = (const float*)d_in[12];
    const float* g2 = (const float*)d_in[13];
    const float* be2 = (const float*)d_in[14];
    const float* g_post = (const float*)d_in[15];
    const float* be_post = (const float*)d_in[16];
    const float* W_out1 = (const float*)d_in[17];
    const float* b_out1 = (const float*)d_in[18];
    const float* g_out = (const float*)d_in[19];
    const float* be_out = (const float*)d_in[20];
    const float* W_out2 = (const float*)d_in[21];
    const float* b_out2 = (const float*)d_in[22];

    const int N = in_sizes[0] / HID;
    const int E = in_sizes[1] / 2;
    const int* srcp = ei;
    const int* dstp = ei + E;

    const int nbk = (N + (1 << BK_SHIFT) - 1) >> BK_SHIFT;
    if (nbk > BK_MAX) return;
    if (N > (1 << 24)) return;

    size_t NODE = (size_t)N * HID;
    float* f = (float*)d_ws;
    float* pre0 = f;
    float* z0 = f + NODE;
    float* z1 = f + 2 * NODE;
    float* z2 = f + 3 * NODE;
    float* o = f + 4 * NODE;        // pairs overlay during CSR build; pst buffer after
    float* p = f + 5 * NODE;
    int* rc = (int*)(f + 6 * NODE);
    int* col = rc + (N + 1);
    int* gh = col + E;
    int* boff = gh + 512;
    int* gcur = boff + 513;
    float* raw = (float*)(gcur + 512);
    unsigned* pairs = (unsigned*)o;

    size_t need = (size_t)(6 * NODE) * 4 + ((size_t)(N + 1) + E + 1537) * 4 + (size_t)11 * 128 * 4;
    if (ws_size < need) return;

    float invN = 1.0f / (float)N;
    int gt = (N + 63) / 64;
    int pb = (E + 256 * PART_EPT - 1) / (256 * PART_EPT);

    hipMemsetAsync(gh, 0, 512 * sizeof(int), stream);

    k_bhist<<<512, 256, 0, stream>>>(dstp, gh, E, nbk);
    k_bscan<<<1, 512, 0, stream>>>(gh, boff, gcur, nbk);
    k_bpart<<<pb, 256, 0, stream>>>(srcp, dstp, gcur, pairs, E);
    k_bucket_csr<<<nbk, 256, 0, stream>>>(pairs, boff, rc, col, N, E, nbk);

    // input projection; partials -> o (pairs consumed), reduce -> raw stage 0
    k_gemm_t64<false, true><<<gt, 256, 0, stream>>>(x, nullptr, nullptr, nullptr, invN,
                                                    W_in, b_in, pre0, o, N);
    k_redstats<<<32, 256, 0, stream>>>(o, raw, gt);

    float* zb[3] = {z0, z1, z2};
    for (int i = 0; i < LAYERS; i++) {
        int s1 = 1 + 3 * i, s2 = 2 + 3 * i, sp = 3 + 3 * i;
        const float* hb = (i == 0) ? pre0 : zb[i - 1];
        const float* rh = (i == 0) ? raw : raw + (size_t)(3 * i) * 128;
        const float* gh2 = (i == 0) ? g_in : g_post + (i - 1) * HID;
        const float* eh = (i == 0) ? be_in : be_post + (i - 1) * HID;
        // FUSED agg + gemm1: p = ((1+eps)*act(hb) + sum act(hb[src])) @ W1 + b1; partials -> zb[i]
        k_agg_gemm<<<gt, 256, 0, stream>>>(hb, rh, gh2, eh, invN, rc, col, epsp, i,
                                           W1 + (size_t)i * HID * HID, b1 + i * HID,
                                           p, zb[i], N);
        k_redstats<<<32, 256, 0, stream>>>(zb[i], raw + (size_t)s1 * 128, gt);
        // gemm2: zb[i] = act(p; s1) @ W2 + b2; partials -> o
        k_gemm_t64<true, true><<<gt, 256, 0, stream>>>(p, raw + (size_t)s1 * 128, g1 + i * HID, be1 + i * HID,
                                                       invN, W2 + (size_t)i * HID * HID, b2 + i * HID,
                                                       zb[i], o, N);
        k_redstats<<<32, 256, 0, stream>>>(o, raw + (size_t)s2 * 128, gt);
        // zb[i] <- relu_aff(zb[i]; s2) in place; partials -> o
        k_affine_stats<<<512, 256, 0, stream>>>(zb[i], raw + (size_t)s2 * 128, g2 + i * HID, be2 + i * HID, invN,
                                                o, (long long)NODE);
        k_redstats<<<32, 256, 0, stream>>>(o, raw + (size_t)sp * 128, 512);
    }

    k_gemm_out1_t<<<gt, 256, 0, stream>>>(pre0, z0, z1, z2,
                                          raw, raw + 3 * 128, raw + 6 * 128, raw + 9 * 128,
                                          g_in, g_post, g_post + HID, g_post + 2 * HID,
                                          be_in, be_post, be_post + HID, be_post + 2 * HID,
                                          invN, W_out1, b_out1, p, o, N);
    k_redstats<<<32, 256, 0, stream>>>(o, raw + 10 * 128, gt);
    k_gemm_out2_t<<<gt, 256, 0, stream>>>(p, raw + 10 * 128, g_out, be_out, invN,
                                          W_out2, b_out2, (float*)d_out, N);
}

// Round 15
// 732.636 us; speedup vs baseline: 1.0868x; 1.0868x over previous
//
#include <hip/hip_runtime.h>

// GIN forward, MI355X. Round 14 (resubmit; prior bench was an infra failure):
//  - REVERT R13's agg+gemm fusion (serialized gather: 16 nodes/wave sequential
//    killed TLP; 111us, FETCH 185MB). Back to standalone pipeline (R8 GEMMs).
//  - NEW k_agg: wave owns a NODE PAIR (CSR edges contiguous). Combined range
//    processed with 32-edge main chunk = 8 col + 8 row loads in flight per lane
//    (2x old peak), geometric 16/8/4/rem drain (old 4-chunk tail was 1-in-flight
//    serialized). A/B classification via running-total: aT += r, aA += r if
//    idx<split, aB = aT-aA (exact when unmixed). Both rows written concurrently
//    (sub==0 -> A, sub==1 -> B).
//  - R8 4x4 LDS GEMMs; partial stats + k_redstats (R6); bucketed CSR (R3).

#define HID 64
#define LAYERS 3
#define BN_EPS 1e-5f

#define BK_SHIFT 8          // 256 nodes per bucket
#define BK_MAX 512          // max buckets supported (N <= 131072)
#define PART_EPT 16         // edges per thread in k_bpart

__device__ __forceinline__ float relu_aff(float x, float s, float t) {
    return fmaxf(fmaf(x, s, t), 0.f);
}

__device__ __forceinline__ void bn_fin(const float* __restrict__ raw, const float* __restrict__ g,
                                       const float* __restrict__ b, float invN, int c,
                                       float& s, float& t) {
    float m = raw[c] * invN;
    float v = fmaf(-m, m, raw[64 + c] * invN);
    float r = rsqrtf(v + BN_EPS);
    s = r * g[c];
    t = fmaf(-m, s, b[c]);
}

// ---------------- bucketed CSR build ----------------

__global__ __launch_bounds__(256) void k_bhist(const int* __restrict__ dst, int* __restrict__ gh,
                                               int E, int nbk) {
    __shared__ int h[BK_MAX];
    for (int i = threadIdx.x; i < BK_MAX; i += 256) h[i] = 0;
    __syncthreads();
    int stride = gridDim.x * 256;
    for (int e = blockIdx.x * 256 + threadIdx.x; e < E; e += stride)
        atomicAdd(&h[dst[e] >> BK_SHIFT], 1);
    __syncthreads();
    for (int i = threadIdx.x; i < nbk; i += 256)
        if (h[i]) atomicAdd(&gh[i], h[i]);
}

__global__ __launch_bounds__(512) void k_bscan(const int* __restrict__ gh, int* __restrict__ boff,
                                               int* __restrict__ gcur, int nbk) {
    int lane = threadIdx.x & 63, wid = threadIdx.x >> 6;
    int v = (threadIdx.x < nbk) ? gh[threadIdx.x] : 0;
    int incl = v;
    for (int d = 1; d < 64; d <<= 1) { int y = __shfl_up(incl, d); if (lane >= d) incl += y; }
    __shared__ int ws[8];
    if (lane == 63) ws[wid] = incl;
    __syncthreads();
    if (threadIdx.x == 0) { int a = 0; for (int w = 0; w < 8; w++) { int t = ws[w]; ws[w] = a; a += t; } }
    __syncthreads();
    int excl = incl - v + ws[wid];
    if (threadIdx.x < nbk) { boff[threadIdx.x] = excl; gcur[threadIdx.x] = excl; }
    if (threadIdx.x == nbk - 1) boff[nbk] = excl + v;
}

__global__ __launch_bounds__(256) void k_bpart(const int* __restrict__ src, const int* __restrict__ dst,
                                               int* __restrict__ gcur, unsigned* __restrict__ pairs,
                                               int E) {
    __shared__ int h[BK_MAX], cur[BK_MAX], base[BK_MAX];
    int e0 = blockIdx.x * (256 * PART_EPT);
    int eend = min(e0 + 256 * PART_EPT, E);
    for (int i = threadIdx.x; i < BK_MAX; i += 256) h[i] = 0;
    __syncthreads();
    for (int e = e0 + threadIdx.x; e < eend; e += 256)
        atomicAdd(&h[dst[e] >> BK_SHIFT], 1);
    __syncthreads();
    for (int i = threadIdx.x; i < BK_MAX; i += 256) {
        cur[i] = 0;
        base[i] = h[i] ? atomicAdd(&gcur[i], h[i]) : 0;
    }
    __syncthreads();
    for (int e = e0 + threadIdx.x; e < eend; e += 256) {
        int d = dst[e];
        int b = d >> BK_SHIFT;
        int r = atomicAdd(&cur[b], 1);
        pairs[base[b] + r] = ((unsigned)(d & ((1 << BK_SHIFT) - 1)) << 24) | (unsigned)src[e];
    }
}

__global__ __launch_bounds__(256) void k_bucket_csr(const unsigned* __restrict__ pairs,
                                                    const int* __restrict__ boff,
                                                    int* __restrict__ row_off, int* __restrict__ col,
                                                    int N, int E, int nbk) {
    int b = blockIdx.x;
    int p0 = boff[b], p1 = boff[b + 1];
    int base_node = b << BK_SHIFT;
    int nn = min(256, N - base_node);
    __shared__ int h[256], cur[256];
    h[threadIdx.x] = 0;
    __syncthreads();
    for (int p = p0 + threadIdx.x; p < p1; p += 256)
        atomicAdd(&h[pairs[p] >> 24], 1);
    __syncthreads();
    int v = h[threadIdx.x];
    int lane = threadIdx.x & 63, wid = threadIdx.x >> 6;
    int incl = v;
    for (int d = 1; d < 64; d <<= 1) { int y = __shfl_up(incl, d); if (lane >= d) incl += y; }
    __shared__ int ws[4];
    if (lane == 63) ws[wid] = incl;
    __syncthreads();
    if (threadIdx.x == 0) { int a = 0; for (int w = 0; w < 4; w++) { int t = ws[w]; ws[w] = a; a += t; } }
    __syncthreads();
    int excl = incl - v + ws[wid];
    if (threadIdx.x < nn) row_off[base_node + threadIdx.x] = p0 + excl;
    if (b == nbk - 1 && threadIdx.x == 0) row_off[N] = E;
    cur[threadIdx.x] = excl;
    __syncthreads();
    for (int p = p0 + threadIdx.x; p < p1; p += 256) {
        unsigned pk = pairs[p];
        int local = pk >> 24;
        int r = atomicAdd(&cur[local], 1);
        col[p0 + r] = (int)(pk & 0xFFFFFFu);
    }
}

// ---------------- partial-stats reduce ----------------
__global__ __launch_bounds__(256) void k_redstats(const float* __restrict__ pst,
                                                  float* __restrict__ rawOut, int nblk) {
    int slot = blockIdx.x * 4 + (threadIdx.x >> 6);  // 0..127
    int lane = threadIdx.x & 63;
    float s = 0.f;
    for (int b = lane; b < nblk; b += 64) s += pst[(size_t)b * 128 + slot];
#pragma unroll
    for (int m = 1; m < 64; m <<= 1) s += __shfl_xor(s, m, 64);
    if (lane == 0) rawOut[slot] = s;
}

// ---------------- aggregation: o = (1+eps)*act(h) + sum act(h[src]) ----------------
// Wave owns node pair (A,B) with contiguous CSR edges [e, e2), split at 'split'.
// 32-edge main chunk: 8 col + 8 row loads in flight/lane. aB = aT - aA.

#define AGG_ACC(V, BASE)                                                    \
    {                                                                       \
        float rx = relu_aff((V).x, s0, t0), ry = relu_aff((V).y, s1, t1);   \
        float rz = relu_aff((V).z, s2, t2), rw = relu_aff((V).w, s3, t3);   \
        aT.x += rx; aT.y += ry; aT.z += rz; aT.w += rw;                     \
        if ((BASE) + sub < split) { aA.x += rx; aA.y += ry; aA.z += rz; aA.w += rw; } \
    }

__global__ __launch_bounds__(256) void k_agg(const float* __restrict__ hb,
                                             const float* __restrict__ raw, const float* __restrict__ g,
                                             const float* __restrict__ b, float invN,
                                             const int* __restrict__ row_off, const int* __restrict__ col,
                                             const float* __restrict__ epsp, int li,
                                             float* __restrict__ o, int n) {
    int wid = threadIdx.x >> 6, lane = threadIdx.x & 63;
    int nodeA = (blockIdx.x * 4 + wid) * 2;
    if (nodeA >= n) return;
    int nodeB = nodeA + 1;
    bool hasB = nodeB < n;
    int sub = lane >> 4;
    int fc = (lane & 15) * 4;
    float s0, t0, s1, t1, s2, t2, s3, t3;
    bn_fin(raw, g, b, invN, fc + 0, s0, t0);
    bn_fin(raw, g, b, invN, fc + 1, s1, t1);
    bn_fin(raw, g, b, invN, fc + 2, s2, t2);
    bn_fin(raw, g, b, invN, fc + 3, s3, t3);

    int e = row_off[nodeA];
    int split = row_off[nodeA + 1];
    int e2 = hasB ? row_off[nodeB + 1] : split;
    float4 aT = make_float4(0.f, 0.f, 0.f, 0.f);
    float4 aA = make_float4(0.f, 0.f, 0.f, 0.f);

    while (e + 32 <= e2) {
        int i0 = col[e + sub],      i1 = col[e + 4 + sub];
        int i2 = col[e + 8 + sub],  i3 = col[e + 12 + sub];
        int i4 = col[e + 16 + sub], i5 = col[e + 20 + sub];
        int i6 = col[e + 24 + sub], i7 = col[e + 28 + sub];
        float4 v0 = *(const float4*)&hb[(size_t)i0 * HID + fc];
        float4 v1 = *(const float4*)&hb[(size_t)i1 * HID + fc];
        float4 v2 = *(const float4*)&hb[(size_t)i2 * HID + fc];
        float4 v3 = *(const float4*)&hb[(size_t)i3 * HID + fc];
        float4 v4 = *(const float4*)&hb[(size_t)i4 * HID + fc];
        float4 v5 = *(const float4*)&hb[(size_t)i5 * HID + fc];
        float4 v6 = *(const float4*)&hb[(size_t)i6 * HID + fc];
        float4 v7 = *(const float4*)&hb[(size_t)i7 * HID + fc];
        AGG_ACC(v0, e +  0) AGG_ACC(v1, e +  4) AGG_ACC(v2, e +  8) AGG_ACC(v3, e + 12)
        AGG_ACC(v4, e + 16) AGG_ACC(v5, e + 20) AGG_ACC(v6, e + 24) AGG_ACC(v7, e + 28)
        e += 32;
    }
    if (e + 16 <= e2) {
        int i0 = col[e + sub],     i1 = col[e + 4 + sub];
        int i2 = col[e + 8 + sub], i3 = col[e + 12 + sub];
        float4 v0 = *(const float4*)&hb[(size_t)i0 * HID + fc];
        float4 v1 = *(const float4*)&hb[(size_t)i1 * HID + fc];
        float4 v2 = *(const float4*)&hb[(size_t)i2 * HID + fc];
        float4 v3 = *(const float4*)&hb[(size_t)i3 * HID + fc];
        AGG_ACC(v0, e + 0) AGG_ACC(v1, e + 4) AGG_ACC(v2, e + 8) AGG_ACC(v3, e + 12)
        e += 16;
    }
    if (e + 8 <= e2) {
        int i0 = col[e + sub], i1 = col[e + 4 + sub];
        float4 v0 = *(const float4*)&hb[(size_t)i0 * HID + fc];
        float4 v1 = *(const float4*)&hb[(size_t)i1 * HID + fc];
        AGG_ACC(v0, e + 0) AGG_ACC(v1, e + 4)
        e += 8;
    }
    if (e + 4 <= e2) {
        int i0 = col[e + sub];
        float4 v0 = *(const float4*)&hb[(size_t)i0 * HID + fc];
        AGG_ACC(v0, e)
        e += 4;
    }
    int rem = e2 - e;
    if (sub < rem) {
        int i0 = col[e + sub];
        float4 v0 = *(const float4*)&hb[(size_t)i0 * HID + fc];
        AGG_ACC(v0, e)
    }

    // reduce across the 4 sub-groups
    aT.x += __shfl_xor(aT.x, 16, 64); aT.y += __shfl_xor(aT.y, 16, 64);
    aT.z += __shfl_xor(aT.z, 16, 64); aT.w += __shfl_xor(aT.w, 16, 64);
    aT.x += __shfl_xor(aT.x, 32, 64); aT.y += __shfl_xor(aT.y, 32, 64);
    aT.z += __shfl_xor(aT.z, 32, 64); aT.w += __shfl_xor(aT.w, 32, 64);
    aA.x += __shfl_xor(aA.x, 16, 64); aA.y += __shfl_xor(aA.y, 16, 64);
    aA.z += __shfl_xor(aA.z, 16, 64); aA.w += __shfl_xor(aA.w, 16, 64);
    aA.x += __shfl_xor(aA.x, 32, 64); aA.y += __shfl_xor(aA.y, 32, 64);
    aA.z += __shfl_xor(aA.z, 32, 64); aA.w += __shfl_xor(aA.w, 32, 64);

    float ope = 1.f + epsp[li];
    if (sub == 0) {
        float4 h4 = *(const float4*)&hb[(size_t)nodeA * HID + fc];
        float4 r;
        r.x = fmaf(ope, relu_aff(h4.x, s0, t0), aA.x);
        r.y = fmaf(ope, relu_aff(h4.y, s1, t1), aA.y);
        r.z = fmaf(ope, relu_aff(h4.z, s2, t2), aA.z);
        r.w = fmaf(ope, relu_aff(h4.w, s3, t3), aA.w);
        *(float4*)&o[(size_t)nodeA * HID + fc] = r;
    } else if (sub == 1 && hasB) {
        float4 h4 = *(const float4*)&hb[(size_t)nodeB * HID + fc];
        float4 r;
        r.x = fmaf(ope, relu_aff(h4.x, s0, t0), aT.x - aA.x);
        r.y = fmaf(ope, relu_aff(h4.y, s1, t1), aT.y - aA.y);
        r.z = fmaf(ope, relu_aff(h4.z, s2, t2), aT.z - aA.z);
        r.w = fmaf(ope, relu_aff(h4.w, s3, t3), aT.w - aA.w);
        *(float4*)&o[(size_t)nodeB * HID + fc] = r;
    }
}

// ---------------- 4x4 register-blocked GEMM core (R8, proven) ----------------
#define GEMM44_COMPUTE(sAT, sW, acc, r0, c0)                                \
    _Pragma("unroll 8")                                                     \
    for (int k = 0; k < HID; k++) {                                         \
        float4 a = *(const float4*)&sAT[k * 65 + r0];                       \
        float4 w = *(const float4*)&sW[k * HID + c0];                       \
        acc[0]  = fmaf(a.x, w.x, acc[0]);  acc[1]  = fmaf(a.x, w.y, acc[1]);\
        acc[2]  = fmaf(a.x, w.z, acc[2]);  acc[3]  = fmaf(a.x, w.w, acc[3]);\
        acc[4]  = fmaf(a.y, w.x, acc[4]);  acc[5]  = fmaf(a.y, w.y, acc[5]);\
        acc[6]  = fmaf(a.y, w.z, acc[6]);  acc[7]  = fmaf(a.y, w.w, acc[7]);\
        acc[8]  = fmaf(a.z, w.x, acc[8]);  acc[9]  = fmaf(a.z, w.y, acc[9]);\
        acc[10] = fmaf(a.z, w.z, acc[10]); acc[11] = fmaf(a.z, w.w, acc[11]);\
        acc[12] = fmaf(a.w, w.x, acc[12]); acc[13] = fmaf(a.w, w.y, acc[13]);\
        acc[14] = fmaf(a.w, w.z, acc[14]); acc[15] = fmaf(a.w, w.w, acc[15]);\
    }

// shared epilogue: bias add, C write, per-column stats partials
#define GEMM44_EPILOGUE(STATS_ON)                                            \
    {                                                                        \
        float4 bs = *(const float4*)&bias[c0];                               \
        float sc[4] = {0.f, 0.f, 0.f, 0.f}, sq[4] = {0.f, 0.f, 0.f, 0.f};    \
        _Pragma("unroll")                                                    \
        for (int ri = 0; ri < 4; ri++) {                                     \
            int row = base + r0 + ri;                                        \
            if (row < n) {                                                   \
                float4 v;                                                    \
                v.x = acc[ri * 4 + 0] + bs.x;                                \
                v.y = acc[ri * 4 + 1] + bs.y;                                \
                v.z = acc[ri * 4 + 2] + bs.z;                                \
                v.w = acc[ri * 4 + 3] + bs.w;                                \
                *(float4*)&C[(size_t)row * HID + c0] = v;                    \
                if (STATS_ON) {                                              \
                    sc[0] += v.x; sq[0] = fmaf(v.x, v.x, sq[0]);             \
                    sc[1] += v.y; sq[1] = fmaf(v.y, v.y, sq[1]);             \
                    sc[2] += v.z; sq[2] = fmaf(v.z, v.z, sq[2]);             \
                    sc[3] += v.w; sq[3] = fmaf(v.w, v.w, sq[3]);             \
                }                                                            \
            }                                                                \
        }                                                                    \
        if (STATS_ON) {                                                      \
            int lane = threadIdx.x & 63, wv = threadIdx.x >> 6;              \
            _Pragma("unroll")                                                \
            for (int j = 0; j < 4; j++) {                                    \
                sc[j] += __shfl_xor(sc[j], 16, 64); sc[j] += __shfl_xor(sc[j], 32, 64); \
                sq[j] += __shfl_xor(sq[j], 16, 64); sq[j] += __shfl_xor(sq[j], 32, 64); \
            }                                                                \
            if (lane < 16) {                                                 \
                *(float4*)&ps[wv][c0] = make_float4(sc[0], sc[1], sc[2], sc[3]); \
                *(float4*)&pq[wv][c0] = make_float4(sq[0], sq[1], sq[2], sq[3]); \
            }                                                                \
            __syncthreads();                                                 \
            if (threadIdx.x < 64) {                                          \
                float s = ps[0][threadIdx.x] + ps[1][threadIdx.x] + ps[2][threadIdx.x] + ps[3][threadIdx.x]; \
                float q = pq[0][threadIdx.x] + pq[1][threadIdx.x] + pq[2][threadIdx.x] + pq[3][threadIdx.x]; \
                pst[(size_t)blockIdx.x * 128 + threadIdx.x] = s;             \
                pst[(size_t)blockIdx.x * 128 + 64 + threadIdx.x] = q;        \
            }                                                                \
        }                                                                    \
    }

// tiled GEMM: C[n x 64] = act(A[n x 64]) @ W[64 x 64] + bias
template <bool AFF, bool STATS>
__global__ __launch_bounds__(256) void k_gemm_t64(const float* __restrict__ A,
                                                  const float* __restrict__ raw, const float* __restrict__ g,
                                                  const float* __restrict__ b, float invN,
                                                  const float* __restrict__ W, const float* __restrict__ bias,
                                                  float* __restrict__ C, float* __restrict__ pst, int n) {
    __shared__ float stl[2 * HID];
    __shared__ float sAT[HID * 65];
    __shared__ float sW[HID * HID];
    __shared__ float ps[4][HID], pq[4][HID];
    if (AFF) {
        if (threadIdx.x < HID) {
            float s, t;
            bn_fin(raw, g, b, invN, threadIdx.x, s, t);
            stl[threadIdx.x] = s;
            stl[HID + threadIdx.x] = t;
        }
        __syncthreads();
    }
    int base = blockIdx.x * 64;
#pragma unroll
    for (int it = 0; it < 4; it++) {                      // stage W
        int idx = it * 256 + threadIdx.x;
        *(float4*)&sW[idx * 4] = *(const float4*)&W[idx * 4];
    }
#pragma unroll
    for (int it = 0; it < 4; it++) {                      // stage A^T (+act), zero-fill
        int idx = it * 256 + threadIdx.x;
        int r = idx >> 4;
        int kc = (idx & 15) * 4;
        float4 v = make_float4(0.f, 0.f, 0.f, 0.f);
        if (base + r < n) {
            v = *(const float4*)&A[(size_t)(base + r) * HID + kc];
            if (AFF) {
                v.x = relu_aff(v.x, stl[kc + 0], stl[HID + kc + 0]);
                v.y = relu_aff(v.y, stl[kc + 1], stl[HID + kc + 1]);
                v.z = relu_aff(v.z, stl[kc + 2], stl[HID + kc + 2]);
                v.w = relu_aff(v.w, stl[kc + 3], stl[HID + kc + 3]);
            }
        }
        sAT[(kc + 0) * 65 + r] = v.x;
        sAT[(kc + 1) * 65 + r] = v.y;
        sAT[(kc + 2) * 65 + r] = v.z;
        sAT[(kc + 3) * 65 + r] = v.w;
    }
    __syncthreads();

    int c0 = (threadIdx.x & 15) * 4;
    int r0 = (threadIdx.x >> 4) * 4;
    float acc[16];
#pragma unroll
    for (int j = 0; j < 16; j++) acc[j] = 0.f;
    GEMM44_COMPUTE(sAT, sW, acc, r0, c0)
    GEMM44_EPILOGUE(STATS)
}

// concat GEMM: C = [act(B0)|act(B1)|act(B2)|act(B3)] @ W[256 x 64] + bias, partial stats
__global__ __launch_bounds__(256) void k_gemm_out1_t(const float* __restrict__ B0, const float* __restrict__ B1,
                                                     const float* __restrict__ B2, const float* __restrict__ B3,
                                                     const float* __restrict__ R0, const float* __restrict__ R1,
                                                     const float* __restrict__ R2, const float* __restrict__ R3,
                                                     const float* __restrict__ G0, const float* __restrict__ G1,
                                                     const float* __restrict__ G2, const float* __restrict__ G3,
                                                     const float* __restrict__ E0, const float* __restrict__ E1,
                                                     const float* __restrict__ E2, const float* __restrict__ E3,
                                                     float invN,
                                                     const float* __restrict__ W, const float* __restrict__ bias,
                                                     float* __restrict__ C, float* __restrict__ pst, int n) {
    __shared__ float stl[4][2 * HID];
    __shared__ float sAT[HID * 65];
    __shared__ float sW[HID * HID];
    __shared__ float ps[4][HID], pq[4][HID];
    {
        int p = threadIdx.x >> 6, c = threadIdx.x & 63;
        const float* rp[4] = {R0, R1, R2, R3};
        const float* gp[4] = {G0, G1, G2, G3};
        const float* ep[4] = {E0, E1, E2, E3};
        float s, t;
        bn_fin(rp[p], gp[p], ep[p], invN, c, s, t);
        stl[p][c] = s;
        stl[p][HID + c] = t;
    }
    __syncthreads();

    int base = blockIdx.x * 64;
    int c0 = (threadIdx.x & 15) * 4;
    int r0 = (threadIdx.x >> 4) * 4;
    float acc[16];
#pragma unroll
    for (int j = 0; j < 16; j++) acc[j] = 0.f;
    const float* bufs[4] = {B0, B1, B2, B3};
#pragma unroll
    for (int pp = 0; pp < 4; pp++) {
        if (pp) __syncthreads();                          // WAR before restage
        const float* Bp = bufs[pp];
        const float* Wp = W + (size_t)pp * HID * HID;
#pragma unroll
        for (int it = 0; it < 4; it++) {
            int idx = it * 256 + threadIdx.x;
            *(float4*)&sW[idx * 4] = *(const float4*)&Wp[idx * 4];
        }
#pragma unroll
        for (int it = 0; it < 4; it++) {
            int idx = it * 256 + threadIdx.x;
            int r = idx >> 4;
            int kc = (idx & 15) * 4;
            float4 v = make_float4(0.f, 0.f, 0.f, 0.f);
            if (base + r < n) {
                v = *(const float4*)&Bp[(size_t)(base + r) * HID + kc];
                v.x = relu_aff(v.x, stl[pp][kc + 0], stl[pp][HID + kc + 0]);
                v.y = relu_aff(v.y, stl[pp][kc + 1], stl[pp][HID + kc + 1]);
                v.z = relu_aff(v.z, stl[pp][kc + 2], stl[pp][HID + kc + 2]);
                v.w = relu_aff(v.w, stl[pp][kc + 3], stl[pp][HID + kc + 3]);
            }
            sAT[(kc + 0) * 65 + r] = v.x;
            sAT[(kc + 1) * 65 + r] = v.y;
            sAT[(kc + 2) * 65 + r] = v.z;
            sAT[(kc + 3) * 65 + r] = v.w;
        }
        __syncthreads();
        GEMM44_COMPUTE(sAT, sW, acc, r0, c0)
    }
    GEMM44_EPILOGUE(true)
}

// final GEMM: C[n x 10] = act(A[n x 64]) @ W[64 x 10] + bias. K split across 4 waves.
__global__ __launch_bounds__(256) void k_gemm_out2_t(const float* __restrict__ A,
                                                     const float* __restrict__ raw, const float* __restrict__ g,
                                                     const float* __restrict__ b, float invN,
                                                     const float* __restrict__ W, const float* __restrict__ bias,
                                                     float* __restrict__ C, int n) {
    __shared__ float stl[2 * HID];
    if (threadIdx.x < HID) {
        float s, t;
        bn_fin(raw, g, b, invN, threadIdx.x, s, t);
        stl[threadIdx.x] = s;
        stl[HID + threadIdx.x] = t;
    }
    __syncthreads();
    int lane = threadIdx.x & 63;
    int wv = threadIdx.x >> 6;
    int k0 = __builtin_amdgcn_readfirstlane(wv * 16);
    int row = blockIdx.x * 64 + lane;
    bool valid = row < n;
    float acc[10];
#pragma unroll
    for (int j = 0; j < 10; j++) acc[j] = 0.f;
    if (valid) {
        const float4* a4 = (const float4*)(A + (size_t)row * HID + k0);
#pragma unroll
        for (int kk = 0; kk < 4; kk++) {
            float4 av = a4[kk];
            float a[4] = {av.x, av.y, av.z, av.w};
#pragma unroll
            for (int u = 0; u < 4; u++) {
                int k = k0 + kk * 4 + u;
                float xv = relu_aff(a[u], stl[k], stl[HID + k]);
#pragma unroll
                for (int j = 0; j < 10; j++) acc[j] = fmaf(xv, W[k * 10 + j], acc[j]);
            }
        }
    }
    __shared__ float part[4][64][10];
#pragma unroll
    for (int j = 0; j < 10; j++) part[wv][lane][j] = acc[j];
    __syncthreads();
    if (wv == 0 && valid) {
        float* cp = C + (size_t)row * 10;
#pragma unroll
        for (int j = 0; j < 10; j++)
            cp[j] = bias[j] + part[0][lane][j] + part[1][lane][j] + part[2][lane][j] + part[3][lane][j];
    }
}

// in-place z = relu_aff(x, s2, t2) + partial stats of z into pst
__global__ __launch_bounds__(256) void k_affine_stats(float* __restrict__ X,
                                                      const float* __restrict__ rawIn,
                                                      const float* __restrict__ g, const float* __restrict__ b,
                                                      float invN,
                                                      float* __restrict__ pst, long long n64) {
    long long stride = (long long)gridDim.x * 256;
    long long i0 = (long long)blockIdx.x * 256 + threadIdx.x;
    int col = threadIdx.x & 63;
    float sA, tA;
    bn_fin(rawIn, g, b, invN, col, sA, tA);
    float s = 0.f, q = 0.f;
    for (long long i = i0; i < n64; i += stride) {
        float v = relu_aff(X[i], sA, tA);
        X[i] = v;
        s += v; q = fmaf(v, v, q);
    }
    __shared__ float ls[256], lq[256];
    ls[threadIdx.x] = s; lq[threadIdx.x] = q;
    __syncthreads();
    if (threadIdx.x < 64) {
        s = ls[threadIdx.x] + ls[threadIdx.x + 64] + ls[threadIdx.x + 128] + ls[threadIdx.x + 192];
        q = lq[threadIdx.x] + lq[threadIdx.x + 64] + lq[threadIdx.x + 128] + lq[threadIdx.x + 192];
        pst[(size_t)blockIdx.x * 128 + col] = s;
        pst[(size_t)blockIdx.x * 128 + 64 + col] = q;
    }
}

extern "C" void kernel_launch(void* const* d_in, const int* in_sizes, int n_in,
                              void* d_out, int out_size, void* d_ws, size_t ws_size,
                              hipStream_t stream) {
    const float* x = (const float*)d_in[0];
    const int* ei = (const int*)d_in[1];
    const float* W_in = (const float*)d_in[2];
    const float* b_in = (const float*)d_in[3];
    const float* g_in = (const float*)d_in[4];
    const float* be_in = (const float*)d_in[5];
    const float* epsp = (const float*)d_in[6];
    const float* W1 = (const float*)d_in[7];
    const float* b1 = (const float*)d_in[8];
    const float* g1 = (const float*)d_in[9];
    const float* be1 = (const float*)d_in[10];
    const float* W2 = (const float*)d_in[11];
    const float* b2 = (const float*)d_in[12];
    const float* g2 = (const float*)d_in[13];
    const float* be2 = (const float*)d_in[14];
    const float* g_post = (const float*)d_in[15];
    const float* be_post = (const float*)d_in[16];
    const float* W_out1 = (const float*)d_in[17];
    const float* b_out1 = (const float*)d_in[18];
    const float* g_out = (const float*)d_in[19];
    const float* be_out = (const float*)d_in[20];
    const float* W_out2 = (const float*)d_in[21];
    const float* b_out2 = (const float*)d_in[22];

    const int N = in_sizes[0] / HID;
    const int E = in_sizes[1] / 2;
    const int* srcp = ei;
    const int* dstp = ei + E;

    const int nbk = (N + (1 << BK_SHIFT) - 1) >> BK_SHIFT;
    if (nbk > BK_MAX) return;
    if (N > (1 << 24)) return;

    size_t NODE = (size_t)N * HID;
    float* f = (float*)d_ws;
    float* pre0 = f;
    float* z0 = f + NODE;
    float* z1 = f + 2 * NODE;
    float* z2 = f + 3 * NODE;
    float* o = f + 4 * NODE;        // pairs overlay during CSR build; agg output; pst buffer
    float* p = f + 5 * NODE;
    int* rc = (int*)(f + 6 * NODE);
    int* col = rc + (N + 1);
    int* gh = col + E;
    int* boff = gh + 512;
    int* gcur = boff + 513;
    float* raw = (float*)(gcur + 512);
    unsigned* pairs = (unsigned*)o;

    size_t need = (size_t)(6 * NODE) * 4 + ((size_t)(N + 1) + E + 1537) * 4 + (size_t)11 * 128 * 4;
    if (ws_size < need) return;

    float invN = 1.0f / (float)N;
    int gt = (N + 63) / 64;
    int ga = (N + 7) / 8;           // k_agg grid: 4 waves x 2 nodes per block
    int pb = (E + 256 * PART_EPT - 1) / (256 * PART_EPT);

    hipMemsetAsync(gh, 0, 512 * sizeof(int), stream);

    k_bhist<<<512, 256, 0, stream>>>(dstp, gh, E, nbk);
    k_bscan<<<1, 512, 0, stream>>>(gh, boff, gcur, nbk);
    k_bpart<<<pb, 256, 0, stream>>>(srcp, dstp, gcur, pairs, E);
    k_bucket_csr<<<nbk, 256, 0, stream>>>(pairs, boff, rc, col, N, E, nbk);

    // input projection; partials -> o (pairs consumed), reduce -> raw stage 0
    k_gemm_t64<false, true><<<gt, 256, 0, stream>>>(x, nullptr, nullptr, nullptr, invN,
                                                    W_in, b_in, pre0, o, N);
    k_redstats<<<32, 256, 0, stream>>>(o, raw, gt);

    float* zb[3] = {z0, z1, z2};
    for (int i = 0; i < LAYERS; i++) {
        int s1 = 1 + 3 * i, s2 = 2 + 3 * i, sp = 3 + 3 * i;
        const float* hb = (i == 0) ? pre0 : zb[i - 1];
        const float* rh = (i == 0) ? raw : raw + (size_t)(3 * i) * 128;
        const float* gh2 = (i == 0) ? g_in : g_post + (i - 1) * HID;
        const float* eh = (i == 0) ? be_in : be_post + (i - 1) * HID;
        k_agg<<<ga, 256, 0, stream>>>(hb, rh, gh2, eh, invN, rc, col, epsp, i, o, N);
        // gemm1: p = o @ W1 + b1; partials -> zb[i] (free until gemm2)
        k_gemm_t64<false, true><<<gt, 256, 0, stream>>>(o, nullptr, nullptr, nullptr, invN,
                                                        W1 + (size_t)i * HID * HID, b1 + i * HID,
                                                        p, zb[i], N);
        k_redstats<<<32, 256, 0, stream>>>(zb[i], raw + (size_t)s1 * 128, gt);
        // gemm2: zb[i] = act(p; s1) @ W2 + b2; partials -> o
        k_gemm_t64<true, true><<<gt, 256, 0, stream>>>(p, raw + (size_t)s1 * 128, g1 + i * HID, be1 + i * HID,
                                                       invN, W2 + (size_t)i * HID * HID, b2 + i * HID,
                                                       zb[i], o, N);
        k_redstats<<<32, 256, 0, stream>>>(o, raw + (size_t)s2 * 128, gt);
        // zb[i] <- relu_aff(zb[i]; s2) in place; partials -> o
        k_affine_stats<<<512, 256, 0, stream>>>(zb[i], raw + (size_t)s2 * 128, g2 + i * HID, be2 + i * HID, invN,
                                                o, (long long)NODE);
        k_redstats<<<32, 256, 0, stream>>>(o, raw + (size_t)sp * 128, 512);
    }

    k_gemm_out1_t<<<gt, 256, 0, stream>>>(pre0, z0, z1, z2,
                                          raw, raw + 3 * 128, raw + 6 * 128, raw + 9 * 128,
                                          g_in, g_post, g_post + HID, g_post + 2 * HID,
                                          be_in, be_post, be_post + HID, be_post + 2 * HID,
                                          invN, W_out1, b_out1, p, o, N);
    k_redstats<<<32, 256, 0, stream>>>(o, raw + 10 * 128, gt);
    k_gemm_out2_t<<<gt, 256, 0, stream>>>(p, raw + 10 * 128, g_out, be_out, invN,
                                          W_out2, b_out2, (float*)d_out, N);
}

// Round 16
// 713.555 us; speedup vs baseline: 1.1158x; 1.0267x over previous
//
#include <hip/hip_runtime.h>

// GIN forward, MI355X. Round 16 — consolidation of measured-best components:
//  - k_agg: R7 single-node-per-wave float4 gather (best measured; R15's paired
//    variant regressed -> gather is L2/L3-BW bound, not latency bound).
//  - Square GEMMs (7x): R11's 8x4 reg-block, 128-row tile, PADR=132 (best total).
//  - out1: R8's 4x4, 64-row tile (67us measured vs 77us as 8x4 - direct A/B).
//  - partial stats + k_redstats (R6); bucketed CSR (R3).

#define HID 64
#define LAYERS 3
#define BN_EPS 1e-5f

#define TR 128              // square-GEMM tile rows
#define PADR 132            // 8x4 sAT row pad

#define BK_SHIFT 8          // 256 nodes per bucket
#define BK_MAX 512          // max buckets supported (N <= 131072)
#define PART_EPT 16         // edges per thread in k_bpart

__device__ __forceinline__ float relu_aff(float x, float s, float t) {
    return fmaxf(fmaf(x, s, t), 0.f);
}

__device__ __forceinline__ void bn_fin(const float* __restrict__ raw, const float* __restrict__ g,
                                       const float* __restrict__ b, float invN, int c,
                                       float& s, float& t) {
    float m = raw[c] * invN;
    float v = fmaf(-m, m, raw[64 + c] * invN);
    float r = rsqrtf(v + BN_EPS);
    s = r * g[c];
    t = fmaf(-m, s, b[c]);
}

// ---------------- bucketed CSR build ----------------

__global__ __launch_bounds__(256) void k_bhist(const int* __restrict__ dst, int* __restrict__ gh,
                                               int E, int nbk) {
    __shared__ int h[BK_MAX];
    for (int i = threadIdx.x; i < BK_MAX; i += 256) h[i] = 0;
    __syncthreads();
    int stride = gridDim.x * 256;
    for (int e = blockIdx.x * 256 + threadIdx.x; e < E; e += stride)
        atomicAdd(&h[dst[e] >> BK_SHIFT], 1);
    __syncthreads();
    for (int i = threadIdx.x; i < nbk; i += 256)
        if (h[i]) atomicAdd(&gh[i], h[i]);
}

__global__ __launch_bounds__(512) void k_bscan(const int* __restrict__ gh, int* __restrict__ boff,
                                               int* __restrict__ gcur, int nbk) {
    int lane = threadIdx.x & 63, wid = threadIdx.x >> 6;
    int v = (threadIdx.x < nbk) ? gh[threadIdx.x] : 0;
    int incl = v;
    for (int d = 1; d < 64; d <<= 1) { int y = __shfl_up(incl, d); if (lane >= d) incl += y; }
    __shared__ int ws[8];
    if (lane == 63) ws[wid] = incl;
    __syncthreads();
    if (threadIdx.x == 0) { int a = 0; for (int w = 0; w < 8; w++) { int t = ws[w]; ws[w] = a; a += t; } }
    __syncthreads();
    int excl = incl - v + ws[wid];
    if (threadIdx.x < nbk) { boff[threadIdx.x] = excl; gcur[threadIdx.x] = excl; }
    if (threadIdx.x == nbk - 1) boff[nbk] = excl + v;
}

__global__ __launch_bounds__(256) void k_bpart(const int* __restrict__ src, const int* __restrict__ dst,
                                               int* __restrict__ gcur, unsigned* __restrict__ pairs,
                                               int E) {
    __shared__ int h[BK_MAX], cur[BK_MAX], base[BK_MAX];
    int e0 = blockIdx.x * (256 * PART_EPT);
    int eend = min(e0 + 256 * PART_EPT, E);
    for (int i = threadIdx.x; i < BK_MAX; i += 256) h[i] = 0;
    __syncthreads();
    for (int e = e0 + threadIdx.x; e < eend; e += 256)
        atomicAdd(&h[dst[e] >> BK_SHIFT], 1);
    __syncthreads();
    for (int i = threadIdx.x; i < BK_MAX; i += 256) {
        cur[i] = 0;
        base[i] = h[i] ? atomicAdd(&gcur[i], h[i]) : 0;
    }
    __syncthreads();
    for (int e = e0 + threadIdx.x; e < eend; e += 256) {
        int d = dst[e];
        int b = d >> BK_SHIFT;
        int r = atomicAdd(&cur[b], 1);
        pairs[base[b] + r] = ((unsigned)(d & ((1 << BK_SHIFT) - 1)) << 24) | (unsigned)src[e];
    }
}

__global__ __launch_bounds__(256) void k_bucket_csr(const unsigned* __restrict__ pairs,
                                                    const int* __restrict__ boff,
                                                    int* __restrict__ row_off, int* __restrict__ col,
                                                    int N, int E, int nbk) {
    int b = blockIdx.x;
    int p0 = boff[b], p1 = boff[b + 1];
    int base_node = b << BK_SHIFT;
    int nn = min(256, N - base_node);
    __shared__ int h[256], cur[256];
    h[threadIdx.x] = 0;
    __syncthreads();
    for (int p = p0 + threadIdx.x; p < p1; p += 256)
        atomicAdd(&h[pairs[p] >> 24], 1);
    __syncthreads();
    int v = h[threadIdx.x];
    int lane = threadIdx.x & 63, wid = threadIdx.x >> 6;
    int incl = v;
    for (int d = 1; d < 64; d <<= 1) { int y = __shfl_up(incl, d); if (lane >= d) incl += y; }
    __shared__ int ws[4];
    if (lane == 63) ws[wid] = incl;
    __syncthreads();
    if (threadIdx.x == 0) { int a = 0; for (int w = 0; w < 4; w++) { int t = ws[w]; ws[w] = a; a += t; } }
    __syncthreads();
    int excl = incl - v + ws[wid];
    if (threadIdx.x < nn) row_off[base_node + threadIdx.x] = p0 + excl;
    if (b == nbk - 1 && threadIdx.x == 0) row_off[N] = E;
    cur[threadIdx.x] = excl;
    __syncthreads();
    for (int p = p0 + threadIdx.x; p < p1; p += 256) {
        unsigned pk = pairs[p];
        int local = pk >> 24;
        int r = atomicAdd(&cur[local], 1);
        col[p0 + r] = (int)(pk & 0xFFFFFFu);
    }
}

// ---------------- partial-stats reduce ----------------
__global__ __launch_bounds__(256) void k_redstats(const float* __restrict__ pst,
                                                  float* __restrict__ rawOut, int nblk) {
    int slot = blockIdx.x * 4 + (threadIdx.x >> 6);  // 0..127
    int lane = threadIdx.x & 63;
    float s = 0.f;
    for (int b = lane; b < nblk; b += 64) s += pst[(size_t)b * 128 + slot];
#pragma unroll
    for (int m = 1; m < 64; m <<= 1) s += __shfl_xor(s, m, 64);
    if (lane == 0) rawOut[slot] = s;
}

// ---------------- aggregation (R7): o = (1+eps)*act(h) + sum act(h[src]) ----------------
__global__ __launch_bounds__(256) void k_agg(const float* __restrict__ hb,
                                             const float* __restrict__ raw, const float* __restrict__ g,
                                             const float* __restrict__ b, float invN,
                                             const int* __restrict__ row_off, const int* __restrict__ col,
                                             const float* __restrict__ epsp, int li,
                                             float* __restrict__ o, int n) {
    int wid = threadIdx.x >> 6, lane = threadIdx.x & 63;
    int node = blockIdx.x * 4 + wid;
    if (node >= n) return;
    int sub = lane >> 4;
    int fc = (lane & 15) * 4;
    float s0, t0, s1, t1, s2, t2, s3, t3;
    bn_fin(raw, g, b, invN, fc + 0, s0, t0);
    bn_fin(raw, g, b, invN, fc + 1, s1, t1);
    bn_fin(raw, g, b, invN, fc + 2, s2, t2);
    bn_fin(raw, g, b, invN, fc + 3, s3, t3);
    float ax = 0.f, ay = 0.f, az = 0.f, aw = 0.f;
    int e = row_off[node], e1 = row_off[node + 1];

    while (e + 16 <= e1) {
        int i0 = col[e + sub], i1 = col[e + 4 + sub], i2 = col[e + 8 + sub], i3 = col[e + 12 + sub];
        float4 v0 = *(const float4*)&hb[(size_t)i0 * HID + fc];
        float4 v1 = *(const float4*)&hb[(size_t)i1 * HID + fc];
        float4 v2 = *(const float4*)&hb[(size_t)i2 * HID + fc];
        float4 v3 = *(const float4*)&hb[(size_t)i3 * HID + fc];
        ax += relu_aff(v0.x, s0, t0) + relu_aff(v1.x, s0, t0) + relu_aff(v2.x, s0, t0) + relu_aff(v3.x, s0, t0);
        ay += relu_aff(v0.y, s1, t1) + relu_aff(v1.y, s1, t1) + relu_aff(v2.y, s1, t1) + relu_aff(v3.y, s1, t1);
        az += relu_aff(v0.z, s2, t2) + relu_aff(v1.z, s2, t2) + relu_aff(v2.z, s2, t2) + relu_aff(v3.z, s2, t2);
        aw += relu_aff(v0.w, s3, t3) + relu_aff(v1.w, s3, t3) + relu_aff(v2.w, s3, t3) + relu_aff(v3.w, s3, t3);
        e += 16;
    }
    while (e + 4 <= e1) {
        int i = col[e + sub];
        float4 v = *(const float4*)&hb[(size_t)i * HID + fc];
        ax += relu_aff(v.x, s0, t0);
        ay += relu_aff(v.y, s1, t1);
        az += relu_aff(v.z, s2, t2);
        aw += relu_aff(v.w, s3, t3);
        e += 4;
    }
    int rem = e1 - e;
    if (sub < rem) {
        int i = col[e + sub];
        float4 v = *(const float4*)&hb[(size_t)i * HID + fc];
        ax += relu_aff(v.x, s0, t0);
        ay += relu_aff(v.y, s1, t1);
        az += relu_aff(v.z, s2, t2);
        aw += relu_aff(v.w, s3, t3);
    }
    ax += __shfl_xor(ax, 16, 64); ay += __shfl_xor(ay, 16, 64);
    az += __shfl_xor(az, 16, 64); aw += __shfl_xor(aw, 16, 64);
    ax += __shfl_xor(ax, 32, 64); ay += __shfl_xor(ay, 32, 64);
    az += __shfl_xor(az, 32, 64); aw += __shfl_xor(aw, 32, 64);
    if (sub == 0) {
        float ope = 1.f + epsp[li];
        float4 h4 = *(const float4*)&hb[(size_t)node * HID + fc];
        float4 r;
        r.x = fmaf(ope, relu_aff(h4.x, s0, t0), ax);
        r.y = fmaf(ope, relu_aff(h4.y, s1, t1), ay);
        r.z = fmaf(ope, relu_aff(h4.z, s2, t2), az);
        r.w = fmaf(ope, relu_aff(h4.w, s3, t3), aw);
        *(float4*)&o[(size_t)node * HID + fc] = r;
    }
}

// ---------------- 8x4 register-blocked GEMM (R11) for the seven 64x64 GEMMs ----------------
#define GEMM84_K(sAT, sW, acc, r0, c0)                                       \
    _Pragma("unroll 4")                                                      \
    for (int k = 0; k < HID; k++) {                                          \
        float4 al = *(const float4*)&sAT[k * PADR + r0];                     \
        float4 ah = *(const float4*)&sAT[k * PADR + r0 + 4];                 \
        float4 w  = *(const float4*)&sW[k * HID + c0];                       \
        acc[0]  = fmaf(al.x, w.x, acc[0]);  acc[1]  = fmaf(al.x, w.y, acc[1]); \
        acc[2]  = fmaf(al.x, w.z, acc[2]);  acc[3]  = fmaf(al.x, w.w, acc[3]); \
        acc[4]  = fmaf(al.y, w.x, acc[4]);  acc[5]  = fmaf(al.y, w.y, acc[5]); \
        acc[6]  = fmaf(al.y, w.z, acc[6]);  acc[7]  = fmaf(al.y, w.w, acc[7]); \
        acc[8]  = fmaf(al.z, w.x, acc[8]);  acc[9]  = fmaf(al.z, w.y, acc[9]); \
        acc[10] = fmaf(al.z, w.z, acc[10]); acc[11] = fmaf(al.z, w.w, acc[11]); \
        acc[12] = fmaf(al.w, w.x, acc[12]); acc[13] = fmaf(al.w, w.y, acc[13]); \
        acc[14] = fmaf(al.w, w.z, acc[14]); acc[15] = fmaf(al.w, w.w, acc[15]); \
        acc[16] = fmaf(ah.x, w.x, acc[16]); acc[17] = fmaf(ah.x, w.y, acc[17]); \
        acc[18] = fmaf(ah.x, w.z, acc[18]); acc[19] = fmaf(ah.x, w.w, acc[19]); \
        acc[20] = fmaf(ah.y, w.x, acc[20]); acc[21] = fmaf(ah.y, w.y, acc[21]); \
        acc[22] = fmaf(ah.y, w.z, acc[22]); acc[23] = fmaf(ah.y, w.w, acc[23]); \
        acc[24] = fmaf(ah.z, w.x, acc[24]); acc[25] = fmaf(ah.z, w.y, acc[25]); \
        acc[26] = fmaf(ah.z, w.z, acc[26]); acc[27] = fmaf(ah.z, w.w, acc[27]); \
        acc[28] = fmaf(ah.w, w.x, acc[28]); acc[29] = fmaf(ah.w, w.y, acc[29]); \
        acc[30] = fmaf(ah.w, w.z, acc[30]); acc[31] = fmaf(ah.w, w.w, acc[31]); \
    }

template <bool AFF, bool STATS>
__global__ __launch_bounds__(256) void k_gemm_t64(const float* __restrict__ A,
                                                  const float* __restrict__ raw, const float* __restrict__ g,
                                                  const float* __restrict__ b, float invN,
                                                  const float* __restrict__ W, const float* __restrict__ bias,
                                                  float* __restrict__ C, float* __restrict__ pst, int n) {
    __shared__ float stl[2 * HID];
    __shared__ float sAT[HID * PADR];
    __shared__ float sW[HID * HID];
    __shared__ float ps[4][HID], pq[4][HID];
    if (AFF) {
        if (threadIdx.x < HID) {
            float s, t;
            bn_fin(raw, g, b, invN, threadIdx.x, s, t);
            stl[threadIdx.x] = s;
            stl[HID + threadIdx.x] = t;
        }
        __syncthreads();
    }
    int base = blockIdx.x * TR;
#pragma unroll
    for (int it = 0; it < 4; it++) {                      // stage W
        int idx = it * 256 + threadIdx.x;
        *(float4*)&sW[idx * 4] = *(const float4*)&W[idx * 4];
    }
#pragma unroll
    for (int it = 0; it < 8; it++) {                      // stage A^T (+act), zero-fill
        int idx = it * 256 + threadIdx.x;                 // 0..2047
        int r = idx >> 4;                                 // 0..127
        int kc = (idx & 15) * 4;
        float4 v = make_float4(0.f, 0.f, 0.f, 0.f);
        if (base + r < n) {
            v = *(const float4*)&A[(size_t)(base + r) * HID + kc];
            if (AFF) {
                v.x = relu_aff(v.x, stl[kc + 0], stl[HID + kc + 0]);
                v.y = relu_aff(v.y, stl[kc + 1], stl[HID + kc + 1]);
                v.z = relu_aff(v.z, stl[kc + 2], stl[HID + kc + 2]);
                v.w = relu_aff(v.w, stl[kc + 3], stl[HID + kc + 3]);
            }
        }
        sAT[(kc + 0) * PADR + r] = v.x;
        sAT[(kc + 1) * PADR + r] = v.y;
        sAT[(kc + 2) * PADR + r] = v.z;
        sAT[(kc + 3) * PADR + r] = v.w;
    }
    __syncthreads();

    int c0 = (threadIdx.x & 15) * 4;
    int r0 = (threadIdx.x >> 4) * 8;
    float acc[32];
#pragma unroll
    for (int j = 0; j < 32; j++) acc[j] = 0.f;
    GEMM84_K(sAT, sW, acc, r0, c0)

    float4 bs = *(const float4*)&bias[c0];
    float sc[4] = {0.f, 0.f, 0.f, 0.f}, sq[4] = {0.f, 0.f, 0.f, 0.f};
#pragma unroll
    for (int ri = 0; ri < 8; ri++) {
        int row = base + r0 + ri;
        if (row < n) {
            float4 v;
            v.x = acc[ri * 4 + 0] + bs.x;
            v.y = acc[ri * 4 + 1] + bs.y;
            v.z = acc[ri * 4 + 2] + bs.z;
            v.w = acc[ri * 4 + 3] + bs.w;
            *(float4*)&C[(size_t)row * HID + c0] = v;
            if (STATS) {
                sc[0] += v.x; sq[0] = fmaf(v.x, v.x, sq[0]);
                sc[1] += v.y; sq[1] = fmaf(v.y, v.y, sq[1]);
                sc[2] += v.z; sq[2] = fmaf(v.z, v.z, sq[2]);
                sc[3] += v.w; sq[3] = fmaf(v.w, v.w, sq[3]);
            }
        }
    }
    if (STATS) {
        int lane = threadIdx.x & 63, wv = threadIdx.x >> 6;
#pragma unroll
        for (int j = 0; j < 4; j++) {
            sc[j] += __shfl_xor(sc[j], 16, 64); sc[j] += __shfl_xor(sc[j], 32, 64);
            sq[j] += __shfl_xor(sq[j], 16, 64); sq[j] += __shfl_xor(sq[j], 32, 64);
        }
        if (lane < 16) {
            *(float4*)&ps[wv][c0] = make_float4(sc[0], sc[1], sc[2], sc[3]);
            *(float4*)&pq[wv][c0] = make_float4(sq[0], sq[1], sq[2], sq[3]);
        }
        __syncthreads();
        if (threadIdx.x < 64) {
            float s = ps[0][threadIdx.x] + ps[1][threadIdx.x] + ps[2][threadIdx.x] + ps[3][threadIdx.x];
            float q = pq[0][threadIdx.x] + pq[1][threadIdx.x] + pq[2][threadIdx.x] + pq[3][threadIdx.x];
            pst[(size_t)blockIdx.x * 128 + threadIdx.x] = s;
            pst[(size_t)blockIdx.x * 128 + 64 + threadIdx.x] = q;
        }
    }
}

// ---------------- 4x4 GEMM core (R8) for out1 ----------------
#define GEMM44_COMPUTE(sAT, sW, acc, r0, c0)                                \
    _Pragma("unroll 8")                                                     \
    for (int k = 0; k < HID; k++) {                                         \
        float4 a = *(const float4*)&sAT[k * 65 + r0];                       \
        float4 w = *(const float4*)&sW[k * HID + c0];                       \
        acc[0]  = fmaf(a.x, w.x, acc[0]);  acc[1]  = fmaf(a.x, w.y, acc[1]);\
        acc[2]  = fmaf(a.x, w.z, acc[2]);  acc[3]  = fmaf(a.x, w.w, acc[3]);\
        acc[4]  = fmaf(a.y, w.x, acc[4]);  acc[5]  = fmaf(a.y, w.y, acc[5]);\
        acc[6]  = fmaf(a.y, w.z, acc[6]);  acc[7]  = fmaf(a.y, w.w, acc[7]);\
        acc[8]  = fmaf(a.z, w.x, acc[8]);  acc[9]  = fmaf(a.z, w.y, acc[9]);\
        acc[10] = fmaf(a.z, w.z, acc[10]); acc[11] = fmaf(a.z, w.w, acc[11]);\
        acc[12] = fmaf(a.w, w.x, acc[12]); acc[13] = fmaf(a.w, w.y, acc[13]);\
        acc[14] = fmaf(a.w, w.z, acc[14]); acc[15] = fmaf(a.w, w.w, acc[15]);\
    }

// concat GEMM: C = [act(B0)|act(B1)|act(B2)|act(B3)] @ W[256 x 64] + bias, partial stats
__global__ __launch_bounds__(256) void k_gemm_out1_t(const float* __restrict__ B0, const float* __restrict__ B1,
                                                     const float* __restrict__ B2, const float* __restrict__ B3,
                                                     const float* __restrict__ R0, const float* __restrict__ R1,
                                                     const float* __restrict__ R2, const float* __restrict__ R3,
                                                     const float* __restrict__ G0, const float* __restrict__ G1,
                                                     const float* __restrict__ G2, const float* __restrict__ G3,
                                                     const float* __restrict__ E0, const float* __restrict__ E1,
                                                     const float* __restrict__ E2, const float* __restrict__ E3,
                                                     float invN,
                                                     const float* __restrict__ W, const float* __restrict__ bias,
                                                     float* __restrict__ C, float* __restrict__ pst, int n) {
    __shared__ float stl[4][2 * HID];
    __shared__ float sAT[HID * 65];
    __shared__ float sW[HID * HID];
    __shared__ float ps[4][HID], pq[4][HID];
    {
        int p = threadIdx.x >> 6, c = threadIdx.x & 63;
        const float* rp[4] = {R0, R1, R2, R3};
        const float* gp[4] = {G0, G1, G2, G3};
        const float* ep[4] = {E0, E1, E2, E3};
        float s, t;
        bn_fin(rp[p], gp[p], ep[p], invN, c, s, t);
        stl[p][c] = s;
        stl[p][HID + c] = t;
    }
    __syncthreads();

    int base = blockIdx.x * 64;
    int c0 = (threadIdx.x & 15) * 4;
    int r0 = (threadIdx.x >> 4) * 4;
    float acc[16];
#pragma unroll
    for (int j = 0; j < 16; j++) acc[j] = 0.f;
    const float* bufs[4] = {B0, B1, B2, B3};
#pragma unroll
    for (int pp = 0; pp < 4; pp++) {
        if (pp) __syncthreads();                          // WAR before restage
        const float* Bp = bufs[pp];
        const float* Wp = W + (size_t)pp * HID * HID;
#pragma unroll
        for (int it = 0; it < 4; it++) {
            int idx = it * 256 + threadIdx.x;
            *(float4*)&sW[idx * 4] = *(const float4*)&Wp[idx * 4];
        }
#pragma unroll
        for (int it = 0; it < 4; it++) {
            int idx = it * 256 + threadIdx.x;
            int r = idx >> 4;
            int kc = (idx & 15) * 4;
            float4 v = make_float4(0.f, 0.f, 0.f, 0.f);
            if (base + r < n) {
                v = *(const float4*)&Bp[(size_t)(base + r) * HID + kc];
                v.x = relu_aff(v.x, stl[pp][kc + 0], stl[pp][HID + kc + 0]);
                v.y = relu_aff(v.y, stl[pp][kc + 1], stl[pp][HID + kc + 1]);
                v.z = relu_aff(v.z, stl[pp][kc + 2], stl[pp][HID + kc + 2]);
                v.w = relu_aff(v.w, stl[pp][kc + 3], stl[pp][HID + kc + 3]);
            }
            sAT[(kc + 0) * 65 + r] = v.x;
            sAT[(kc + 1) * 65 + r] = v.y;
            sAT[(kc + 2) * 65 + r] = v.z;
            sAT[(kc + 3) * 65 + r] = v.w;
        }
        __syncthreads();
        GEMM44_COMPUTE(sAT, sW, acc, r0, c0)
    }

    float4 bs = *(const float4*)&bias[c0];
    float sc[4] = {0.f, 0.f, 0.f, 0.f}, sq[4] = {0.f, 0.f, 0.f, 0.f};
#pragma unroll
    for (int ri = 0; ri < 4; ri++) {
        int row = base + r0 + ri;
        if (row < n) {
            float4 v;
            v.x = acc[ri * 4 + 0] + bs.x;
            v.y = acc[ri * 4 + 1] + bs.y;
            v.z = acc[ri * 4 + 2] + bs.z;
            v.w = acc[ri * 4 + 3] + bs.w;
            *(float4*)&C[(size_t)row * HID + c0] = v;
            sc[0] += v.x; sq[0] = fmaf(v.x, v.x, sq[0]);
            sc[1] += v.y; sq[1] = fmaf(v.y, v.y, sq[1]);
            sc[2] += v.z; sq[2] = fmaf(v.z, v.z, sq[2]);
            sc[3] += v.w; sq[3] = fmaf(v.w, v.w, sq[3]);
        }
    }
    int lane = threadIdx.x & 63, wv = threadIdx.x >> 6;
#pragma unroll
    for (int j = 0; j < 4; j++) {
        sc[j] += __shfl_xor(sc[j], 16, 64); sc[j] += __shfl_xor(sc[j], 32, 64);
        sq[j] += __shfl_xor(sq[j], 16, 64); sq[j] += __shfl_xor(sq[j], 32, 64);
    }
    if (lane < 16) {
        *(float4*)&ps[wv][c0] = make_float4(sc[0], sc[1], sc[2], sc[3]);
        *(float4*)&pq[wv][c0] = make_float4(sq[0], sq[1], sq[2], sq[3]);
    }
    __syncthreads();
    if (threadIdx.x < 64) {
        float s = ps[0][threadIdx.x] + ps[1][threadIdx.x] + ps[2][threadIdx.x] + ps[3][threadIdx.x];
        float q = pq[0][threadIdx.x] + pq[1][threadIdx.x] + pq[2][threadIdx.x] + pq[3][threadIdx.x];
        pst[(size_t)blockIdx.x * 128 + threadIdx.x] = s;
        pst[(size_t)blockIdx.x * 128 + 64 + threadIdx.x] = q;
    }
}

// final GEMM: C[n x 10] = act(A[n x 64]) @ W[64 x 10] + bias. K split across 4 waves.
__global__ __launch_bounds__(256) void k_gemm_out2_t(const float* __restrict__ A,
                                                     const float* __restrict__ raw, const float* __restrict__ g,
                                                     const float* __restrict__ b, float invN,
                                                     const float* __restrict__ W, const float* __restrict__ bias,
                                                     float* __restrict__ C, int n) {
    __shared__ float stl[2 * HID];
    if (threadIdx.x < HID) {
        float s, t;
        bn_fin(raw, g, b, invN, threadIdx.x, s, t);
        stl[threadIdx.x] = s;
        stl[HID + threadIdx.x] = t;
    }
    __syncthreads();
    int lane = threadIdx.x & 63;
    int wv = threadIdx.x >> 6;
    int k0 = __builtin_amdgcn_readfirstlane(wv * 16);
    int row = blockIdx.x * 64 + lane;
    bool valid = row < n;
    float acc[10];
#pragma unroll
    for (int j = 0; j < 10; j++) acc[j] = 0.f;
    if (valid) {
        const float4* a4 = (const float4*)(A + (size_t)row * HID + k0);
#pragma unroll
        for (int kk = 0; kk < 4; kk++) {
            float4 av = a4[kk];
            float a[4] = {av.x, av.y, av.z, av.w};
#pragma unroll
            for (int u = 0; u < 4; u++) {
                int k = k0 + kk * 4 + u;
                float xv = relu_aff(a[u], stl[k], stl[HID + k]);
#pragma unroll
                for (int j = 0; j < 10; j++) acc[j] = fmaf(xv, W[k * 10 + j], acc[j]);
            }
        }
    }
    __shared__ float part[4][64][10];
#pragma unroll
    for (int j = 0; j < 10; j++) part[wv][lane][j] = acc[j];
    __syncthreads();
    if (wv == 0 && valid) {
        float* cp = C + (size_t)row * 10;
#pragma unroll
        for (int j = 0; j < 10; j++)
            cp[j] = bias[j] + part[0][lane][j] + part[1][lane][j] + part[2][lane][j] + part[3][lane][j];
    }
}

// in-place z = relu_aff(x, s2, t2) + partial stats of z into pst
__global__ __launch_bounds__(256) void k_affine_stats(float* __restrict__ X,
                                                      const float* __restrict__ rawIn,
                                                      const float* __restrict__ g, const float* __restrict__ b,
                                                      float invN,
                                                      float* __restrict__ pst, long long n64) {
    long long stride = (long long)gridDim.x * 256;
    long long i0 = (long long)blockIdx.x * 256 + threadIdx.x;
    int col = threadIdx.x & 63;
    float sA, tA;
    bn_fin(rawIn, g, b, invN, col, sA, tA);
    float s = 0.f, q = 0.f;
    for (long long i = i0; i < n64; i += stride) {
        float v = relu_aff(X[i], sA, tA);
        X[i] = v;
        s += v; q = fmaf(v, v, q);
    }
    __shared__ float ls[256], lq[256];
    ls[threadIdx.x] = s; lq[threadIdx.x] = q;
    __syncthreads();
    if (threadIdx.x < 64) {
        s = ls[threadIdx.x] + ls[threadIdx.x + 64] + ls[threadIdx.x + 128] + ls[threadIdx.x + 192];
        q = lq[threadIdx.x] + lq[threadIdx.x + 64] + lq[threadIdx.x + 128] + lq[threadIdx.x + 192];
        pst[(size_t)blockIdx.x * 128 + col] = s;
        pst[(size_t)blockIdx.x * 128 + 64 + col] = q;
    }
}

extern "C" void kernel_launch(void* const* d_in, const int* in_sizes, int n_in,
                              void* d_out, int out_size, void* d_ws, size_t ws_size,
                              hipStream_t stream) {
    const float* x = (const float*)d_in[0];
    const int* ei = (const int*)d_in[1];
    const float* W_in = (const float*)d_in[2];
    const float* b_in = (const float*)d_in[3];
    const float* g_in = (const float*)d_in[4];
    const float* be_in = (const float*)d_in[5];
    const float* epsp = (const float*)d_in[6];
    const float* W1 = (const float*)d_in[7];
    const float* b1 = (const float*)d_in[8];
    const float* g1 = (const float*)d_in[9];
    const float* be1 = (const float*)d_in[10];
    const float* W2 = (const float*)d_in[11];
    const float* b2 = (const float*)d_in[12];
    const float* g2 = (const float*)d_in[13];
    const float* be2 = (const float*)d_in[14];
    const float* g_post = (const float*)d_in[15];
    const float* be_post = (const float*)d_in[16];
    const float* W_out1 = (const float*)d_in[17];
    const float* b_out1 = (const float*)d_in[18];
    const float* g_out = (const float*)d_in[19];
    const float* be_out = (const float*)d_in[20];
    const float* W_out2 = (const float*)d_in[21];
    const float* b_out2 = (const float*)d_in[22];

    const int N = in_sizes[0] / HID;
    const int E = in_sizes[1] / 2;
    const int* srcp = ei;
    const int* dstp = ei + E;

    const int nbk = (N + (1 << BK_SHIFT) - 1) >> BK_SHIFT;
    if (nbk > BK_MAX) return;
    if (N > (1 << 24)) return;

    size_t NODE = (size_t)N * HID;
    float* f = (float*)d_ws;
    float* pre0 = f;
    float* z0 = f + NODE;
    float* z1 = f + 2 * NODE;
    float* z2 = f + 3 * NODE;
    float* o = f + 4 * NODE;        // pairs overlay during CSR build; agg output; pst buffer
    float* p = f + 5 * NODE;
    int* rc = (int*)(f + 6 * NODE);
    int* col = rc + (N + 1);
    int* gh = col + E;
    int* boff = gh + 512;
    int* gcur = boff + 513;
    float* raw = (float*)(gcur + 512);
    unsigned* pairs = (unsigned*)o;

    size_t need = (size_t)(6 * NODE) * 4 + ((size_t)(N + 1) + E + 1537) * 4 + (size_t)11 * 128 * 4;
    if (ws_size < need) return;

    float invN = 1.0f / (float)N;
    int gt128 = (N + TR - 1) / TR;      // 8x4 square-GEMM grid (782)
    int gt64 = (N + 63) / 64;           // out1/out2 grid (1563)
    int ga = (N + 3) / 4;               // k_agg grid
    int pb = (E + 256 * PART_EPT - 1) / (256 * PART_EPT);

    hipMemsetAsync(gh, 0, 512 * sizeof(int), stream);

    k_bhist<<<512, 256, 0, stream>>>(dstp, gh, E, nbk);
    k_bscan<<<1, 512, 0, stream>>>(gh, boff, gcur, nbk);
    k_bpart<<<pb, 256, 0, stream>>>(srcp, dstp, gcur, pairs, E);
    k_bucket_csr<<<nbk, 256, 0, stream>>>(pairs, boff, rc, col, N, E, nbk);

    // input projection; partials -> o (pairs consumed), reduce -> raw stage 0
    k_gemm_t64<false, true><<<gt128, 256, 0, stream>>>(x, nullptr, nullptr, nullptr, invN,
                                                       W_in, b_in, pre0, o, N);
    k_redstats<<<32, 256, 0, stream>>>(o, raw, gt128);

    float* zb[3] = {z0, z1, z2};
    for (int i = 0; i < LAYERS; i++) {
        int s1 = 1 + 3 * i, s2 = 2 + 3 * i, sp = 3 + 3 * i;
        const float* hb = (i == 0) ? pre0 : zb[i - 1];
        const float* rh = (i == 0) ? raw : raw + (size_t)(3 * i) * 128;
        const float* gh2 = (i == 0) ? g_in : g_post + (i - 1) * HID;
        const float* eh = (i == 0) ? be_in : be_post + (i - 1) * HID;
        k_agg<<<ga, 256, 0, stream>>>(hb, rh, gh2, eh, invN, rc, col, epsp, i, o, N);
        // gemm1: p = o @ W1 + b1; partials -> zb[i] (free until gemm2)
        k_gemm_t64<false, true><<<gt128, 256, 0, stream>>>(o, nullptr, nullptr, nullptr, invN,
                                                           W1 + (size_t)i * HID * HID, b1 + i * HID,
                                                           p, zb[i], N);
        k_redstats<<<32, 256, 0, stream>>>(zb[i], raw + (size_t)s1 * 128, gt128);
        // gemm2: zb[i] = act(p; s1) @ W2 + b2; partials -> o
        k_gemm_t64<true, true><<<gt128, 256, 0, stream>>>(p, raw + (size_t)s1 * 128, g1 + i * HID, be1 + i * HID,
                                                          invN, W2 + (size_t)i * HID * HID, b2 + i * HID,
                                                          zb[i], o, N);
        k_redstats<<<32, 256, 0, stream>>>(o, raw + (size_t)s2 * 128, gt128);
        // zb[i] <- relu_aff(zb[i]; s2) in place; partials -> o
        k_affine_stats<<<512, 256, 0, stream>>>(zb[i], raw + (size_t)s2 * 128, g2 + i * HID, be2 + i * HID, invN,
                                                o, (long long)NODE);
        k_redstats<<<32, 256, 0, stream>>>(o, raw + (size_t)sp * 128, 512);
    }

    k_gemm_out1_t<<<gt64, 256, 0, stream>>>(pre0, z0, z1, z2,
                                            raw, raw + 3 * 128, raw + 6 * 128, raw + 9 * 128,
                                            g_in, g_post, g_post + HID, g_post + 2 * HID,
                                            be_in, be_post, be_post + HID, be_post + 2 * HID,
                                            invN, W_out1, b_out1, p, o, N);
    k_redstats<<<32, 256, 0, stream>>>(o, raw + 10 * 128, gt64);
    k_gemm_out2_t<<<gt64, 256, 0, stream>>>(p, raw + 10 * 128, g_out, be_out, invN,
                                            W_out2, b_out2, (float*)d_out, N);
}